// Round 1
// baseline (1789.076 us; speedup 1.0000x reference)
//
#include <hip/hip_runtime.h>
#include <hip/hip_bf16.h>
#include <cstddef>

#define N_NODES 100000
#define N_EDGES 1600000

// ---------------------------------------------------------------- CSR build
__global__ void hist_kernel(const int* __restrict__ dst, int* __restrict__ deg) {
    int e = blockIdx.x * 256 + threadIdx.x;
    if (e < N_EDGES) atomicAdd(&deg[dst[e]], 1);
}

__global__ void scan_block_kernel(const int* __restrict__ deg, int* __restrict__ rowptr,
                                  int* __restrict__ bsum) {
    __shared__ int s[256];
    int t = threadIdx.x;
    int base = blockIdx.x * 1024 + t * 4;
    int v[4]; int sum = 0;
#pragma unroll
    for (int j = 0; j < 4; ++j) { v[j] = (base + j < N_NODES) ? deg[base + j] : 0; sum += v[j]; }
    s[t] = sum; __syncthreads();
    for (int off = 1; off < 256; off <<= 1) {
        int x = (t >= off) ? s[t - off] : 0;
        __syncthreads();
        s[t] += x;
        __syncthreads();
    }
    int excl = (t > 0) ? s[t - 1] : 0;
    if (t == 255) bsum[blockIdx.x] = s[255];
    int run = excl;
#pragma unroll
    for (int j = 0; j < 4; ++j) { if (base + j < N_NODES) rowptr[base + j] = run; run += v[j]; }
}

__global__ void scan_bsum_kernel(int* bsum, int nb) {
    __shared__ int s[128];
    int t = threadIdx.x;
    int v = (t < nb) ? bsum[t] : 0;
    s[t] = v; __syncthreads();
    for (int off = 1; off < 128; off <<= 1) {
        int x = (t >= off) ? s[t - off] : 0;
        __syncthreads();
        s[t] += x;
        __syncthreads();
    }
    if (t < nb) bsum[t] = (t > 0) ? s[t - 1] : 0;
}

__global__ void scan_add_kernel(int* __restrict__ rowptr, const int* __restrict__ bsum) {
    int i = blockIdx.x * 256 + threadIdx.x;
    if (i < N_NODES) rowptr[i] += bsum[i >> 10];
    if (i == 0) rowptr[N_NODES] = N_EDGES;
}

__global__ void scatter_kernel(const int* __restrict__ src, const int* __restrict__ dst,
                               const int* __restrict__ rowptr, int* __restrict__ fill,
                               int* __restrict__ csr_src) {
    int e = blockIdx.x * 256 + threadIdx.x;
    if (e < N_EDGES) {
        int d = dst[e];
        int pos = rowptr[d] + atomicAdd(&fill[d], 1);
        csr_src[pos] = src[e];
    }
}

// ---------------------------------------------------------------- GEMM (K=128)
// C[M, Ncols] = A[M,128] @ W[128, Ncols].  Tile: 64 rows x 128 cols.
__global__ __launch_bounds__(256) void gemm128_kernel(const float* __restrict__ A,
                                                      const float* __restrict__ W,
                                                      float* __restrict__ C,
                                                      int M, int Ncols) {
    __shared__ float Ws[128 * 128];   // [k][c], 64KB
    __shared__ float Xs[64 * 129];    // [r][k] padded, ~33KB
    int tid = threadIdx.x;
    int rt = blockIdx.x * 64;
    int ct = blockIdx.y * 128;

    for (int i = tid; i < 4096; i += 256) {               // 128x32 float4
        int k = i >> 5, c4 = i & 31;
        *reinterpret_cast<float4*>(&Ws[k * 128 + c4 * 4]) =
            *reinterpret_cast<const float4*>(W + (size_t)k * Ncols + ct + c4 * 4);
    }
    for (int i = tid; i < 2048; i += 256) {               // 64x32 float4
        int r = i >> 5, c4 = i & 31;
        int row = rt + r;
        float4 v = make_float4(0.f, 0.f, 0.f, 0.f);
        if (row < M) v = *reinterpret_cast<const float4*>(A + (size_t)row * 128 + c4 * 4);
        float* xp = &Xs[r * 129 + c4 * 4];
        xp[0] = v.x; xp[1] = v.y; xp[2] = v.z; xp[3] = v.w;
    }
    __syncthreads();

    int r = tid & 63;          // row within tile
    int q = tid >> 6;          // col group (32 cols)
    float acc[32];
#pragma unroll
    for (int i = 0; i < 32; ++i) acc[i] = 0.f;

#pragma unroll 4
    for (int k = 0; k < 128; ++k) {
        float xr = Xs[r * 129 + k];
#pragma unroll
        for (int j = 0; j < 8; ++j) {
            float4 wv = *reinterpret_cast<const float4*>(&Ws[k * 128 + q * 32 + j * 4]);
            acc[j * 4 + 0] = fmaf(xr, wv.x, acc[j * 4 + 0]);
            acc[j * 4 + 1] = fmaf(xr, wv.y, acc[j * 4 + 1]);
            acc[j * 4 + 2] = fmaf(xr, wv.z, acc[j * 4 + 2]);
            acc[j * 4 + 3] = fmaf(xr, wv.w, acc[j * 4 + 3]);
        }
    }
    int row = rt + r;
    if (row < M) {
#pragma unroll
        for (int j = 0; j < 8; ++j) {
            float4 o = make_float4(acc[j * 4 + 0], acc[j * 4 + 1], acc[j * 4 + 2], acc[j * 4 + 3]);
            *reinterpret_cast<float4*>(C + (size_t)row * Ncols + ct + q * 32 + j * 4) = o;
        }
    }
}

// ---------------------------------------------------------------- el/er dot products
template <int D>
__global__ void attn_scores_kernel(const float* __restrict__ h, const float* __restrict__ al,
                                   const float* __restrict__ ar, float* __restrict__ el,
                                   float* __restrict__ er) {
    int t = blockIdx.x * 256 + threadIdx.x;
    if (t >= N_NODES * 4) return;
    int n = t >> 2, hh = t & 3;
    const float* hp = h + (size_t)n * (4 * D) + hh * D;
    const float* alp = al + hh * D;
    const float* arp = ar + hh * D;
    float sl = 0.f, sr = 0.f;
#pragma unroll
    for (int d = 0; d < D; d += 4) {
        float4 hv = *reinterpret_cast<const float4*>(hp + d);
        float4 av = *reinterpret_cast<const float4*>(alp + d);
        float4 rv = *reinterpret_cast<const float4*>(arp + d);
        sl += hv.x * av.x + hv.y * av.y + hv.z * av.z + hv.w * av.w;
        sr += hv.x * rv.x + hv.y * rv.y + hv.z * rv.z + hv.w * rv.w;
    }
    el[t] = sl;
    er[t] = sr;
}

// ---------------------------------------------------------------- edge softmax + aggregate
// MODE 0: elu activation, write [N,4*D].  MODE 1: mean over heads, write [N,D].
template <int D, int MODE>
__global__ __launch_bounds__(4 * D) void aggregate_kernel(
    const float* __restrict__ hfeat, const float* __restrict__ el, const float* __restrict__ er,
    const int* __restrict__ rowptr, const int* __restrict__ csr_src,
    const float* __restrict__ bias, float* __restrict__ out) {
    int n = blockIdx.x;
    int f = threadIdx.x;          // 0 .. 4D-1
    int hh = f / D;
    int row0 = rowptr[n], row1 = rowptr[n + 1];
    float er_n = er[n * 4 + hh];

    float m = -INFINITY;
    for (int i = row0; i < row1; ++i) {
        int s = csr_src[i];
        float sc = el[s * 4 + hh] + er_n;
        sc = sc > 0.f ? sc : 0.2f * sc;
        m = fmaxf(m, sc);
    }
    float denom = 0.f, acc = 0.f;
    for (int i = row0; i < row1; ++i) {
        int s = csr_src[i];
        float sc = el[s * 4 + hh] + er_n;
        sc = sc > 0.f ? sc : 0.2f * sc;
        float ee = __expf(sc - m);
        denom += ee;
        acc = fmaf(ee, hfeat[(size_t)s * (4 * D) + f], acc);
    }
    float val = (row1 > row0) ? acc / denom : 0.f;
    val += bias[f];
    if (MODE == 0) {
        val = val > 0.f ? val : (__expf(val) - 1.f);
        out[(size_t)n * (4 * D) + f] = val;
    } else {
        __shared__ float sh[4 * D];
        sh[f] = val;
        __syncthreads();
        if (f < D)
            out[(size_t)n * D + f] = 0.25f * (sh[f] + sh[D + f] + sh[2 * D + f] + sh[3 * D + f]);
    }
}

// ---------------------------------------------------------------- launch
extern "C" void kernel_launch(void* const* d_in, const int* in_sizes, int n_in,
                              void* d_out, int out_size, void* d_ws, size_t ws_size,
                              hipStream_t stream) {
    const float* nfeat = (const float*)d_in[0];
    const int* src = (const int*)d_in[1];
    const int* dst = (const int*)d_in[2];
    const float* W0 = (const float*)d_in[3];
    const float* al0 = (const float*)d_in[4];
    const float* ar0 = (const float*)d_in[5];
    const float* b0 = (const float*)d_in[6];
    const float* W1 = (const float*)d_in[7];
    const float* al1 = (const float*)d_in[8];
    const float* ar1 = (const float*)d_in[9];
    const float* b1 = (const float*)d_in[10];
    const float* W2 = (const float*)d_in[11];
    const float* al2 = (const float*)d_in[12];
    const float* ar2 = (const float*)d_in[13];
    const float* b2 = (const float*)d_in[14];
    float* out = (float*)d_out;

    char* w = (char*)d_ws;
    float* P = (float*)w;      w += (size_t)N_NODES * 128 * 4;   // 51.2 MB
    float* Q = (float*)w;      w += (size_t)N_NODES * 128 * 4;   // 51.2 MB
    float* R = (float*)w;      w += (size_t)N_NODES * 256 * 4;   // 102.4 MB
    float* el = (float*)w;     w += (size_t)N_NODES * 4 * 4;
    float* er = (float*)w;     w += (size_t)N_NODES * 4 * 4;
    int* rowptr = (int*)w;     w += (size_t)(N_NODES + 4) * 4;
    int* deg = (int*)w;        w += (size_t)N_NODES * 4;
    int* bsum = (int*)w;       w += 256 * 4;
    int* csr_src = (int*)w;    w += (size_t)N_EDGES * 4;

    const int nb_scan = (N_NODES + 1023) / 1024;                 // 98

    // ---- CSR build (once, reused by all 3 layers)
    hipMemsetAsync(deg, 0, (size_t)N_NODES * 4, stream);
    hist_kernel<<<(N_EDGES + 255) / 256, 256, 0, stream>>>(dst, deg);
    scan_block_kernel<<<nb_scan, 256, 0, stream>>>(deg, rowptr, bsum);
    scan_bsum_kernel<<<1, 128, 0, stream>>>(bsum, nb_scan);
    scan_add_kernel<<<(N_NODES + 256) / 256, 256, 0, stream>>>(rowptr, bsum);
    hipMemsetAsync(deg, 0, (size_t)N_NODES * 4, stream);         // reuse as fill counter
    scatter_kernel<<<(N_EDGES + 255) / 256, 256, 0, stream>>>(src, dst, rowptr, deg, csr_src);

    dim3 gemm_block(256);
    dim3 gemm_grid1((N_NODES + 63) / 64, 1);
    dim3 gemm_grid2((N_NODES + 63) / 64, 2);
    const int sc_blocks = (N_NODES * 4 + 255) / 256;

    // ---- Layer 0: nfeat @ W0 -> P ; aggregate -> Q (elu)
    gemm128_kernel<<<gemm_grid1, gemm_block, 0, stream>>>(nfeat, W0, P, N_NODES, 128);
    attn_scores_kernel<32><<<sc_blocks, 256, 0, stream>>>(P, al0, ar0, el, er);
    aggregate_kernel<32, 0><<<N_NODES, 128, 0, stream>>>(P, el, er, rowptr, csr_src, b0, Q);

    // ---- Layer 1: Q @ W1 -> P ; aggregate -> Q (elu)
    gemm128_kernel<<<gemm_grid1, gemm_block, 0, stream>>>(Q, W1, P, N_NODES, 128);
    attn_scores_kernel<32><<<sc_blocks, 256, 0, stream>>>(P, al1, ar1, el, er);
    aggregate_kernel<32, 0><<<N_NODES, 128, 0, stream>>>(P, el, er, rowptr, csr_src, b1, Q);

    // ---- Layer 2: Q @ W2 -> R ; aggregate + head-mean -> out
    gemm128_kernel<<<gemm_grid2, gemm_block, 0, stream>>>(Q, W2, R, N_NODES, 256);
    attn_scores_kernel<64><<<sc_blocks, 256, 0, stream>>>(R, al2, ar2, el, er);
    aggregate_kernel<64, 1><<<N_NODES, 256, 0, stream>>>(R, el, er, rowptr, csr_src, b2, out);
}

// Round 2
// 1344.446 us; speedup vs baseline: 1.3307x; 1.3307x over previous
//
#include <hip/hip_runtime.h>
#include <hip/hip_bf16.h>
#include <cstddef>

#define N_NODES 100000
#define N_EDGES 1600000

// ---------------------------------------------------------------- CSR build
__global__ void hist_kernel(const int* __restrict__ dst, int* __restrict__ deg) {
    int e = blockIdx.x * 256 + threadIdx.x;
    if (e < N_EDGES) atomicAdd(&deg[dst[e]], 1);
}

__global__ void scan_block_kernel(const int* __restrict__ deg, int* __restrict__ rowptr,
                                  int* __restrict__ bsum) {
    __shared__ int s[256];
    int t = threadIdx.x;
    int base = blockIdx.x * 1024 + t * 4;
    int v[4]; int sum = 0;
#pragma unroll
    for (int j = 0; j < 4; ++j) { v[j] = (base + j < N_NODES) ? deg[base + j] : 0; sum += v[j]; }
    s[t] = sum; __syncthreads();
    for (int off = 1; off < 256; off <<= 1) {
        int x = (t >= off) ? s[t - off] : 0;
        __syncthreads();
        s[t] += x;
        __syncthreads();
    }
    int excl = (t > 0) ? s[t - 1] : 0;
    if (t == 255) bsum[blockIdx.x] = s[255];
    int run = excl;
#pragma unroll
    for (int j = 0; j < 4; ++j) { if (base + j < N_NODES) rowptr[base + j] = run; run += v[j]; }
}

__global__ void scan_bsum_kernel(int* bsum, int nb) {
    __shared__ int s[128];
    int t = threadIdx.x;
    int v = (t < nb) ? bsum[t] : 0;
    s[t] = v; __syncthreads();
    for (int off = 1; off < 128; off <<= 1) {
        int x = (t >= off) ? s[t - off] : 0;
        __syncthreads();
        s[t] += x;
        __syncthreads();
    }
    if (t < nb) bsum[t] = (t > 0) ? s[t - 1] : 0;
}

__global__ void scan_add_kernel(int* __restrict__ rowptr, const int* __restrict__ bsum) {
    int i = blockIdx.x * 256 + threadIdx.x;
    if (i < N_NODES) rowptr[i] += bsum[i >> 10];
    if (i == 0) rowptr[N_NODES] = N_EDGES;
}

__global__ void scatter_kernel(const int* __restrict__ src, const int* __restrict__ dst,
                               const int* __restrict__ rowptr, int* __restrict__ fill,
                               int* __restrict__ csr_src) {
    int e = blockIdx.x * 256 + threadIdx.x;
    if (e < N_EDGES) {
        int d = dst[e];
        int pos = rowptr[d] + atomicAdd(&fill[d], 1);
        csr_src[pos] = src[e];
    }
}

// ---------------------------------------------------------------- GEMM (K=128)
__global__ __launch_bounds__(256) void gemm128_kernel(const float* __restrict__ A,
                                                      const float* __restrict__ W,
                                                      float* __restrict__ C,
                                                      int M, int Ncols) {
    __shared__ float Ws[128 * 128];
    __shared__ float Xs[64 * 129];
    int tid = threadIdx.x;
    int rt = blockIdx.x * 64;
    int ct = blockIdx.y * 128;

    for (int i = tid; i < 4096; i += 256) {
        int k = i >> 5, c4 = i & 31;
        *reinterpret_cast<float4*>(&Ws[k * 128 + c4 * 4]) =
            *reinterpret_cast<const float4*>(W + (size_t)k * Ncols + ct + c4 * 4);
    }
    for (int i = tid; i < 2048; i += 256) {
        int r = i >> 5, c4 = i & 31;
        int row = rt + r;
        float4 v = make_float4(0.f, 0.f, 0.f, 0.f);
        if (row < M) v = *reinterpret_cast<const float4*>(A + (size_t)row * 128 + c4 * 4);
        float* xp = &Xs[r * 129 + c4 * 4];
        xp[0] = v.x; xp[1] = v.y; xp[2] = v.z; xp[3] = v.w;
    }
    __syncthreads();

    int r = tid & 63;
    int q = tid >> 6;
    float acc[32];
#pragma unroll
    for (int i = 0; i < 32; ++i) acc[i] = 0.f;

#pragma unroll 4
    for (int k = 0; k < 128; ++k) {
        float xr = Xs[r * 129 + k];
#pragma unroll
        for (int j = 0; j < 8; ++j) {
            float4 wv = *reinterpret_cast<const float4*>(&Ws[k * 128 + q * 32 + j * 4]);
            acc[j * 4 + 0] = fmaf(xr, wv.x, acc[j * 4 + 0]);
            acc[j * 4 + 1] = fmaf(xr, wv.y, acc[j * 4 + 1]);
            acc[j * 4 + 2] = fmaf(xr, wv.z, acc[j * 4 + 2]);
            acc[j * 4 + 3] = fmaf(xr, wv.w, acc[j * 4 + 3]);
        }
    }
    int row = rt + r;
    if (row < M) {
#pragma unroll
        for (int j = 0; j < 8; ++j) {
            float4 o = make_float4(acc[j * 4 + 0], acc[j * 4 + 1], acc[j * 4 + 2], acc[j * 4 + 3]);
            *reinterpret_cast<float4*>(C + (size_t)row * Ncols + ct + q * 32 + j * 4) = o;
        }
    }
}

// ---------------------------------------------------------------- el/er dot products
template <int D>
__global__ void attn_scores_kernel(const float* __restrict__ h, const float* __restrict__ al,
                                   const float* __restrict__ ar, float* __restrict__ el,
                                   float* __restrict__ er) {
    int t = blockIdx.x * 256 + threadIdx.x;
    if (t >= N_NODES * 4) return;
    int n = t >> 2, hh = t & 3;
    const float* hp = h + (size_t)n * (4 * D) + hh * D;
    const float* alp = al + hh * D;
    const float* arp = ar + hh * D;
    float sl = 0.f, sr = 0.f;
#pragma unroll
    for (int d = 0; d < D; d += 4) {
        float4 hv = *reinterpret_cast<const float4*>(hp + d);
        float4 av = *reinterpret_cast<const float4*>(alp + d);
        float4 rv = *reinterpret_cast<const float4*>(arp + d);
        sl += hv.x * av.x + hv.y * av.y + hv.z * av.z + hv.w * av.w;
        sr += hv.x * rv.x + hv.y * rv.y + hv.z * rv.z + hv.w * rv.w;
    }
    el[t] = sl;
    er[t] = sr;
}

// ---------------------------------------------------------------- softmax weights
// wave per node: compute leaky scores for all 4 heads, segment max+sum via
// butterfly shuffles, write unnormalized ee[e][4] + per-node denom[n][4].
__global__ __launch_bounds__(256) void alpha_kernel(
    const float* __restrict__ el, const float* __restrict__ er,
    const int* __restrict__ rowptr, const int* __restrict__ csr_src,
    float* __restrict__ ee, float* __restrict__ denom) {
    int wid = (blockIdx.x * 256 + threadIdx.x) >> 6;
    int lane = threadIdx.x & 63;
    if (wid >= N_NODES) return;
    int row0 = rowptr[wid], row1 = rowptr[wid + 1];
    float4 ern = *reinterpret_cast<const float4*>(er + (size_t)wid * 4);

    float4 mx = make_float4(-INFINITY, -INFINITY, -INFINITY, -INFINITY);
    for (int base = row0; base < row1; base += 64) {
        int i = base + lane;
        if (i < row1) {
            int s = csr_src[i];
            float4 e4 = *reinterpret_cast<const float4*>(el + (size_t)s * 4);
            float4 sc;
            sc.x = e4.x + ern.x; sc.x = sc.x > 0.f ? sc.x : 0.2f * sc.x;
            sc.y = e4.y + ern.y; sc.y = sc.y > 0.f ? sc.y : 0.2f * sc.y;
            sc.z = e4.z + ern.z; sc.z = sc.z > 0.f ? sc.z : 0.2f * sc.z;
            sc.w = e4.w + ern.w; sc.w = sc.w > 0.f ? sc.w : 0.2f * sc.w;
            mx.x = fmaxf(mx.x, sc.x); mx.y = fmaxf(mx.y, sc.y);
            mx.z = fmaxf(mx.z, sc.z); mx.w = fmaxf(mx.w, sc.w);
        }
    }
#pragma unroll
    for (int off = 1; off < 64; off <<= 1) {
        mx.x = fmaxf(mx.x, __shfl_xor(mx.x, off));
        mx.y = fmaxf(mx.y, __shfl_xor(mx.y, off));
        mx.z = fmaxf(mx.z, __shfl_xor(mx.z, off));
        mx.w = fmaxf(mx.w, __shfl_xor(mx.w, off));
    }

    float4 sum = make_float4(0.f, 0.f, 0.f, 0.f);
    for (int base = row0; base < row1; base += 64) {
        int i = base + lane;
        if (i < row1) {
            int s = csr_src[i];
            float4 e4 = *reinterpret_cast<const float4*>(el + (size_t)s * 4);
            float4 sc;
            sc.x = e4.x + ern.x; sc.x = sc.x > 0.f ? sc.x : 0.2f * sc.x;
            sc.y = e4.y + ern.y; sc.y = sc.y > 0.f ? sc.y : 0.2f * sc.y;
            sc.z = e4.z + ern.z; sc.z = sc.z > 0.f ? sc.z : 0.2f * sc.z;
            sc.w = e4.w + ern.w; sc.w = sc.w > 0.f ? sc.w : 0.2f * sc.w;
            float4 e;
            e.x = __expf(sc.x - mx.x); e.y = __expf(sc.y - mx.y);
            e.z = __expf(sc.z - mx.z); e.w = __expf(sc.w - mx.w);
            sum.x += e.x; sum.y += e.y; sum.z += e.z; sum.w += e.w;
            *reinterpret_cast<float4*>(ee + (size_t)i * 4) = e;
        }
    }
#pragma unroll
    for (int off = 1; off < 64; off <<= 1) {
        sum.x += __shfl_xor(sum.x, off);
        sum.y += __shfl_xor(sum.y, off);
        sum.z += __shfl_xor(sum.z, off);
        sum.w += __shfl_xor(sum.w, off);
    }
    if (lane == 0) *reinterpret_cast<float4*>(denom + (size_t)wid * 4) = sum;
}

// ---------------------------------------------------------------- weighted gather
// wave per node; lane owns V=F/64 consecutive feats. Chunk csr_src load is
// cooperative (coalesced); inner loop: shfl(s) + broadcast ee load + gather.
// MODE 0: elu -> out[N,F].  MODE 1: head-mean -> out[N,F/4].
template <int F, int MODE>
__global__ __launch_bounds__(256) void gather_kernel(
    const float* __restrict__ hfeat, const float* __restrict__ ee,
    const float* __restrict__ denom, const int* __restrict__ rowptr,
    const int* __restrict__ csr_src, const float* __restrict__ bias,
    float* __restrict__ out) {
    constexpr int V = F / 64;      // 2 or 4
    constexpr int D = F / 4;
    int wid = (blockIdx.x * 256 + threadIdx.x) >> 6;
    int lane = threadIdx.x & 63;
    if (wid >= N_NODES) return;
    int row0 = rowptr[wid], row1 = rowptr[wid + 1];
    int f0 = lane * V;
    int hh = f0 / D;

    float acc[V];
#pragma unroll
    for (int v = 0; v < V; ++v) acc[v] = 0.f;

    for (int base = row0; base < row1; base += 64) {
        int i = base + lane;
        int sv = (i < row1) ? csr_src[i] : 0;
        int cnt = min(64, row1 - base);
        const float* eep = ee + (size_t)base * 4 + hh;
        for (int j = 0; j < cnt; ++j) {
            int s = __shfl(sv, j);
            float w = eep[(size_t)j * 4];
            const float* hp = hfeat + (size_t)s * F + f0;
            if (V == 4) {
                float4 hv = *reinterpret_cast<const float4*>(hp);
                acc[0] = fmaf(w, hv.x, acc[0]);
                acc[1] = fmaf(w, hv.y, acc[1]);
                acc[2] = fmaf(w, hv.z, acc[2]);
                acc[3] = fmaf(w, hv.w, acc[3]);
            } else {
                float2 hv = *reinterpret_cast<const float2*>(hp);
                acc[0] = fmaf(w, hv.x, acc[0]);
                acc[1] = fmaf(w, hv.y, acc[1]);
            }
        }
    }

    float dn = denom[(size_t)wid * 4 + hh];
    float inv = dn > 0.f ? 1.f / dn : 0.f;
    float val[V];
#pragma unroll
    for (int v = 0; v < V; ++v) val[v] = acc[v] * inv + bias[f0 + v];

    if (MODE == 0) {
#pragma unroll
        for (int v = 0; v < V; ++v)
            val[v] = val[v] > 0.f ? val[v] : (__expf(val[v]) - 1.f);
        if (V == 2) {
            *reinterpret_cast<float2*>(out + (size_t)wid * F + f0) = make_float2(val[0], val[1]);
        } else {
            *reinterpret_cast<float4*>(out + (size_t)wid * F + f0) =
                make_float4(val[0], val[1], val[2], val[3]);
        }
    } else {
        // mean over 4 heads: lanes l, l^16, l^32, l^48 hold same d, diff head
#pragma unroll
        for (int v = 0; v < V; ++v) {
            val[v] += __shfl_xor(val[v], 16);
            val[v] += __shfl_xor(val[v], 32);
        }
        if (lane < 16) {
            float4 o = make_float4(val[0] * 0.25f, val[1] * 0.25f, val[2] * 0.25f, val[3] * 0.25f);
            *reinterpret_cast<float4*>(out + (size_t)wid * D + lane * 4) = o;
        }
    }
}

// ---------------------------------------------------------------- launch
extern "C" void kernel_launch(void* const* d_in, const int* in_sizes, int n_in,
                              void* d_out, int out_size, void* d_ws, size_t ws_size,
                              hipStream_t stream) {
    const float* nfeat = (const float*)d_in[0];
    const int* src = (const int*)d_in[1];
    const int* dst = (const int*)d_in[2];
    const float* W0 = (const float*)d_in[3];
    const float* al0 = (const float*)d_in[4];
    const float* ar0 = (const float*)d_in[5];
    const float* b0 = (const float*)d_in[6];
    const float* W1 = (const float*)d_in[7];
    const float* al1 = (const float*)d_in[8];
    const float* ar1 = (const float*)d_in[9];
    const float* b1 = (const float*)d_in[10];
    const float* W2 = (const float*)d_in[11];
    const float* al2 = (const float*)d_in[12];
    const float* ar2 = (const float*)d_in[13];
    const float* b2 = (const float*)d_in[14];
    float* out = (float*)d_out;

    char* w = (char*)d_ws;
    float* P = (float*)w;      w += (size_t)N_NODES * 128 * 4;   // 51.2 MB
    float* Q = (float*)w;      w += (size_t)N_NODES * 128 * 4;   // 51.2 MB
    float* R = (float*)w;      w += (size_t)N_NODES * 256 * 4;   // 102.4 MB
    float* el = (float*)w;     w += (size_t)N_NODES * 4 * 4;
    float* er = (float*)w;     w += (size_t)N_NODES * 4 * 4;
    float* denom = (float*)w;  w += (size_t)N_NODES * 4 * 4;
    int* rowptr = (int*)w;     w += (size_t)(N_NODES + 4) * 4;
    int* deg = (int*)w;        w += (size_t)N_NODES * 4;
    int* bsum = (int*)w;       w += 256 * 4;
    int* csr_src = (int*)w;    w += (size_t)N_EDGES * 4;

    // ee aliases dead workspace: layers 0/1 use R (unused until layer-2 GEMM),
    // layer 2 uses Q (dead after layer-2 GEMM reads it).
    float* ee01 = R;
    float* ee2  = Q;

    const int nb_scan = (N_NODES + 1023) / 1024;

    // ---- CSR build (once, reused by all 3 layers)
    hipMemsetAsync(deg, 0, (size_t)N_NODES * 4, stream);
    hist_kernel<<<(N_EDGES + 255) / 256, 256, 0, stream>>>(dst, deg);
    scan_block_kernel<<<nb_scan, 256, 0, stream>>>(deg, rowptr, bsum);
    scan_bsum_kernel<<<1, 128, 0, stream>>>(bsum, nb_scan);
    scan_add_kernel<<<(N_NODES + 256) / 256, 256, 0, stream>>>(rowptr, bsum);
    hipMemsetAsync(deg, 0, (size_t)N_NODES * 4, stream);
    scatter_kernel<<<(N_EDGES + 255) / 256, 256, 0, stream>>>(src, dst, rowptr, deg, csr_src);

    dim3 gemm_block(256);
    dim3 gemm_grid1((N_NODES + 63) / 64, 1);
    dim3 gemm_grid2((N_NODES + 63) / 64, 2);
    const int sc_blocks = (N_NODES * 4 + 255) / 256;
    const int nw_blocks = (N_NODES + 3) / 4;     // wave-per-node kernels

    // ---- Layer 0
    gemm128_kernel<<<gemm_grid1, gemm_block, 0, stream>>>(nfeat, W0, P, N_NODES, 128);
    attn_scores_kernel<32><<<sc_blocks, 256, 0, stream>>>(P, al0, ar0, el, er);
    alpha_kernel<<<nw_blocks, 256, 0, stream>>>(el, er, rowptr, csr_src, ee01, denom);
    gather_kernel<128, 0><<<nw_blocks, 256, 0, stream>>>(P, ee01, denom, rowptr, csr_src, b0, Q);

    // ---- Layer 1
    gemm128_kernel<<<gemm_grid1, gemm_block, 0, stream>>>(Q, W1, P, N_NODES, 128);
    attn_scores_kernel<32><<<sc_blocks, 256, 0, stream>>>(P, al1, ar1, el, er);
    alpha_kernel<<<nw_blocks, 256, 0, stream>>>(el, er, rowptr, csr_src, ee01, denom);
    gather_kernel<128, 0><<<nw_blocks, 256, 0, stream>>>(P, ee01, denom, rowptr, csr_src, b1, Q);

    // ---- Layer 2 (R = Q @ W2; Q dead afterwards -> reuse as ee)
    gemm128_kernel<<<gemm_grid2, gemm_block, 0, stream>>>(Q, W2, R, N_NODES, 256);
    attn_scores_kernel<64><<<sc_blocks, 256, 0, stream>>>(R, al2, ar2, el, er);
    alpha_kernel<<<nw_blocks, 256, 0, stream>>>(el, er, rowptr, csr_src, ee2, denom);
    gather_kernel<256, 1><<<nw_blocks, 256, 0, stream>>>(R, ee2, denom, rowptr, csr_src, b2, out);
}

// Round 3
// 1068.114 us; speedup vs baseline: 1.6750x; 1.2587x over previous
//
#include <hip/hip_runtime.h>
#include <hip/hip_bf16.h>
#include <cstddef>
#include <cstdint>

#define N_NODES 100000
#define N_EDGES 1600000

typedef __attribute__((ext_vector_type(8))) short bf16x8;
typedef __attribute__((ext_vector_type(4))) float f32x4;

__device__ inline unsigned short f2bf(float x) {
    unsigned int u = __float_as_uint(x);
    unsigned int r = (u + 0x7fffu + ((u >> 16) & 1u)) >> 16;
    return (unsigned short)r;
}
__device__ inline float bf2f(unsigned short b) {
    return __uint_as_float((unsigned int)b << 16);
}

// ---------------------------------------------------------------- CSR build
__global__ void hist_kernel(const int* __restrict__ dst, int* __restrict__ deg) {
    int e = blockIdx.x * 256 + threadIdx.x;
    if (e < N_EDGES) atomicAdd(&deg[dst[e]], 1);
}

__global__ void scan_block_kernel(const int* __restrict__ deg, int* __restrict__ rowptr,
                                  int* __restrict__ bsum) {
    __shared__ int s[256];
    int t = threadIdx.x;
    int base = blockIdx.x * 1024 + t * 4;
    int v[4]; int sum = 0;
#pragma unroll
    for (int j = 0; j < 4; ++j) { v[j] = (base + j < N_NODES) ? deg[base + j] : 0; sum += v[j]; }
    s[t] = sum; __syncthreads();
    for (int off = 1; off < 256; off <<= 1) {
        int x = (t >= off) ? s[t - off] : 0;
        __syncthreads();
        s[t] += x;
        __syncthreads();
    }
    int excl = (t > 0) ? s[t - 1] : 0;
    if (t == 255) bsum[blockIdx.x] = s[255];
    int run = excl;
#pragma unroll
    for (int j = 0; j < 4; ++j) { if (base + j < N_NODES) rowptr[base + j] = run; run += v[j]; }
}

__global__ void scan_bsum_kernel(int* bsum, int nb) {
    __shared__ int s[128];
    int t = threadIdx.x;
    int v = (t < nb) ? bsum[t] : 0;
    s[t] = v; __syncthreads();
    for (int off = 1; off < 128; off <<= 1) {
        int x = (t >= off) ? s[t - off] : 0;
        __syncthreads();
        s[t] += x;
        __syncthreads();
    }
    if (t < nb) bsum[t] = (t > 0) ? s[t - 1] : 0;
}

__global__ void scan_add_kernel(int* __restrict__ rowptr, const int* __restrict__ bsum) {
    int i = blockIdx.x * 256 + threadIdx.x;
    if (i < N_NODES) rowptr[i] += bsum[i >> 10];
    if (i == 0) rowptr[N_NODES] = N_EDGES;
}

__global__ void scatter_kernel(const int* __restrict__ src, const int* __restrict__ dst,
                               const int* __restrict__ rowptr, int* __restrict__ fill,
                               int* __restrict__ csr_src) {
    int e = blockIdx.x * 256 + threadIdx.x;
    if (e < N_EDGES) {
        int d = dst[e];
        int pos = rowptr[d] + atomicAdd(&fill[d], 1);
        csr_src[pos] = src[e];
    }
}

// ---------------------------------------------------------------- fp32 -> bf16 hi/lo converts
__global__ __launch_bounds__(256) void convert_x_kernel(const float* __restrict__ X,
                                                        unsigned short* __restrict__ hi,
                                                        unsigned short* __restrict__ lo) {
    size_t t = blockIdx.x * 256 + threadIdx.x;   // one thread per 8 elems; grid exact
    float4 v0 = *reinterpret_cast<const float4*>(X + t * 8);
    float4 v1 = *reinterpret_cast<const float4*>(X + t * 8 + 4);
    float xs[8] = {v0.x, v0.y, v0.z, v0.w, v1.x, v1.y, v1.z, v1.w};
    unsigned int hp[4], lp[4];
#pragma unroll
    for (int j = 0; j < 4; ++j) {
        unsigned short h0 = f2bf(xs[2 * j]), h1 = f2bf(xs[2 * j + 1]);
        unsigned short l0 = f2bf(xs[2 * j] - bf2f(h0));
        unsigned short l1 = f2bf(xs[2 * j + 1] - bf2f(h1));
        hp[j] = (unsigned int)h0 | ((unsigned int)h1 << 16);
        lp[j] = (unsigned int)l0 | ((unsigned int)l1 << 16);
    }
    *reinterpret_cast<uint4*>(hi + t * 8) = make_uint4(hp[0], hp[1], hp[2], hp[3]);
    *reinterpret_cast<uint4*>(lo + t * 8) = make_uint4(lp[0], lp[1], lp[2], lp[3]);
}

// W [128][Ncols] fp32 -> Wt_hi/lo [Ncols][128] bf16 (transposed)
__global__ __launch_bounds__(256) void convert_w_kernel(const float* __restrict__ W,
                                                        unsigned short* __restrict__ Wth,
                                                        unsigned short* __restrict__ Wtl,
                                                        int Ncols) {
    int t = blockIdx.x * 256 + threadIdx.x;
    if (t >= 128 * Ncols) return;
    int n = t >> 7, k = t & 127;
    float x = W[(size_t)k * Ncols + n];
    unsigned short h = f2bf(x);
    unsigned short l = f2bf(x - bf2f(h));
    Wth[t] = h;
    Wtl[t] = l;
}

// ---------------------------------------------------------------- MFMA split-bf16 GEMM
// C[M, ldC] (+128-col slab per blockIdx.y) = (Xhi+Xlo)[M,128] @ (Wth+Wtl)^T.
// Tile 128 rows x 128 cols, 4 waves (wave = 32 rows). K=128 staged in LDS.
__global__ __launch_bounds__(256) void mfma_gemm_kernel(
    const unsigned short* __restrict__ Xhi, const unsigned short* __restrict__ Xlo,
    const unsigned short* __restrict__ Wth, const unsigned short* __restrict__ Wtl,
    float* __restrict__ C, int M, int ldC) {
    __shared__ unsigned short AH[128 * 136];   // padded row-major, conflict-free
    __shared__ unsigned short AL[128 * 136];
    const int tid = threadIdx.x;
    const int wave = tid >> 6, lane = tid & 63;
    const int r = lane & 15, kg = lane >> 4;
    const int row0 = blockIdx.x * 128;
    const int col0 = blockIdx.y * 128;

    // stage X hi/lo tile: 4096 16B chunks, coalesced global reads
#pragma unroll
    for (int i = 0; i < 16; ++i) {
        int sa = i * 256 + tid;
        int a = sa >> 11;
        int s = sa & 2047;
        int rr = s >> 4;
        int u = s & 15;
        const unsigned short* srcp = (a ? Xlo : Xhi) + (size_t)(row0 + rr) * 128 + u * 8;
        unsigned short* dstp = (a ? AL : AH) + rr * 136 + u * 8;
        *reinterpret_cast<uint4*>(dstp) = *reinterpret_cast<const uint4*>(srcp);
    }
    __syncthreads();

    f32x4 acc[2][8];
#pragma unroll
    for (int rt = 0; rt < 2; ++rt)
#pragma unroll
        for (int ct = 0; ct < 8; ++ct)
            acc[rt][ct] = (f32x4){0.f, 0.f, 0.f, 0.f};

#pragma unroll
    for (int ks = 0; ks < 4; ++ks) {
        bf16x8 bh[8], bl[8];
#pragma unroll
        for (int ct = 0; ct < 8; ++ct) {
            size_t off = (size_t)(col0 + ct * 16 + r) * 128 + ks * 32 + kg * 8;
            bh[ct] = *reinterpret_cast<const bf16x8*>(Wth + off);
            bl[ct] = *reinterpret_cast<const bf16x8*>(Wtl + off);
        }
#pragma unroll
        for (int rt = 0; rt < 2; ++rt) {
            int lrow = wave * 32 + rt * 16 + r;
            bf16x8 ah = *reinterpret_cast<const bf16x8*>(&AH[lrow * 136 + ks * 32 + kg * 8]);
            bf16x8 al = *reinterpret_cast<const bf16x8*>(&AL[lrow * 136 + ks * 32 + kg * 8]);
#pragma unroll
            for (int ct = 0; ct < 8; ++ct) {
                acc[rt][ct] = __builtin_amdgcn_mfma_f32_16x16x32_bf16(ah, bh[ct], acc[rt][ct], 0, 0, 0);
                acc[rt][ct] = __builtin_amdgcn_mfma_f32_16x16x32_bf16(al, bh[ct], acc[rt][ct], 0, 0, 0);
                acc[rt][ct] = __builtin_amdgcn_mfma_f32_16x16x32_bf16(ah, bl[ct], acc[rt][ct], 0, 0, 0);
            }
        }
    }

#pragma unroll
    for (int rt = 0; rt < 2; ++rt) {
#pragma unroll
        for (int j = 0; j < 4; ++j) {
            int grow = row0 + wave * 32 + rt * 16 + kg * 4 + j;
            if (grow < M) {
#pragma unroll
                for (int ct = 0; ct < 8; ++ct)
                    C[(size_t)grow * ldC + col0 + ct * 16 + r] = acc[rt][ct][j];
            }
        }
    }
}

// ---------------------------------------------------------------- el/er dot products
template <int D>
__global__ void attn_scores_kernel(const float* __restrict__ h, const float* __restrict__ al,
                                   const float* __restrict__ ar, float* __restrict__ el,
                                   float* __restrict__ er) {
    int t = blockIdx.x * 256 + threadIdx.x;
    if (t >= N_NODES * 4) return;
    int n = t >> 2, hh = t & 3;
    const float* hp = h + (size_t)n * (4 * D) + hh * D;
    const float* alp = al + hh * D;
    const float* arp = ar + hh * D;
    float sl = 0.f, sr = 0.f;
#pragma unroll
    for (int d = 0; d < D; d += 4) {
        float4 hv = *reinterpret_cast<const float4*>(hp + d);
        float4 av = *reinterpret_cast<const float4*>(alp + d);
        float4 rv = *reinterpret_cast<const float4*>(arp + d);
        sl += hv.x * av.x + hv.y * av.y + hv.z * av.z + hv.w * av.w;
        sr += hv.x * rv.x + hv.y * rv.y + hv.z * rv.z + hv.w * rv.w;
    }
    el[t] = sl;
    er[t] = sr;
}

// ---------------------------------------------------------------- softmax weights
__global__ __launch_bounds__(256) void alpha_kernel(
    const float* __restrict__ el, const float* __restrict__ er,
    const int* __restrict__ rowptr, const int* __restrict__ csr_src,
    float* __restrict__ ee, float* __restrict__ denom) {
    int wid = (blockIdx.x * 256 + threadIdx.x) >> 6;
    int lane = threadIdx.x & 63;
    if (wid >= N_NODES) return;
    int row0 = rowptr[wid], row1 = rowptr[wid + 1];
    float4 ern = *reinterpret_cast<const float4*>(er + (size_t)wid * 4);

    float4 mx = make_float4(-INFINITY, -INFINITY, -INFINITY, -INFINITY);
    for (int base = row0; base < row1; base += 64) {
        int i = base + lane;
        if (i < row1) {
            int s = csr_src[i];
            float4 e4 = *reinterpret_cast<const float4*>(el + (size_t)s * 4);
            float4 sc;
            sc.x = e4.x + ern.x; sc.x = sc.x > 0.f ? sc.x : 0.2f * sc.x;
            sc.y = e4.y + ern.y; sc.y = sc.y > 0.f ? sc.y : 0.2f * sc.y;
            sc.z = e4.z + ern.z; sc.z = sc.z > 0.f ? sc.z : 0.2f * sc.z;
            sc.w = e4.w + ern.w; sc.w = sc.w > 0.f ? sc.w : 0.2f * sc.w;
            mx.x = fmaxf(mx.x, sc.x); mx.y = fmaxf(mx.y, sc.y);
            mx.z = fmaxf(mx.z, sc.z); mx.w = fmaxf(mx.w, sc.w);
        }
    }
#pragma unroll
    for (int off = 1; off < 64; off <<= 1) {
        mx.x = fmaxf(mx.x, __shfl_xor(mx.x, off));
        mx.y = fmaxf(mx.y, __shfl_xor(mx.y, off));
        mx.z = fmaxf(mx.z, __shfl_xor(mx.z, off));
        mx.w = fmaxf(mx.w, __shfl_xor(mx.w, off));
    }

    float4 sum = make_float4(0.f, 0.f, 0.f, 0.f);
    for (int base = row0; base < row1; base += 64) {
        int i = base + lane;
        if (i < row1) {
            int s = csr_src[i];
            float4 e4 = *reinterpret_cast<const float4*>(el + (size_t)s * 4);
            float4 sc;
            sc.x = e4.x + ern.x; sc.x = sc.x > 0.f ? sc.x : 0.2f * sc.x;
            sc.y = e4.y + ern.y; sc.y = sc.y > 0.f ? sc.y : 0.2f * sc.y;
            sc.z = e4.z + ern.z; sc.z = sc.z > 0.f ? sc.z : 0.2f * sc.z;
            sc.w = e4.w + ern.w; sc.w = sc.w > 0.f ? sc.w : 0.2f * sc.w;
            float4 e;
            e.x = __expf(sc.x - mx.x); e.y = __expf(sc.y - mx.y);
            e.z = __expf(sc.z - mx.z); e.w = __expf(sc.w - mx.w);
            sum.x += e.x; sum.y += e.y; sum.z += e.z; sum.w += e.w;
            *reinterpret_cast<float4*>(ee + (size_t)i * 4) = e;
        }
    }
#pragma unroll
    for (int off = 1; off < 64; off <<= 1) {
        sum.x += __shfl_xor(sum.x, off);
        sum.y += __shfl_xor(sum.y, off);
        sum.z += __shfl_xor(sum.z, off);
        sum.w += __shfl_xor(sum.w, off);
    }
    if (lane == 0) *reinterpret_cast<float4*>(denom + (size_t)wid * 4) = sum;
}

// ---------------------------------------------------------------- weighted gather
// MODE 0: elu -> bf16 hi/lo [N,F] (feeds next GEMM).  MODE 1: head-mean -> out[N,F/4] fp32.
template <int F, int MODE>
__global__ __launch_bounds__(256) void gather_kernel(
    const float* __restrict__ hfeat, const float* __restrict__ ee,
    const float* __restrict__ denom, const int* __restrict__ rowptr,
    const int* __restrict__ csr_src, const float* __restrict__ bias,
    float* __restrict__ out, unsigned short* __restrict__ ohi,
    unsigned short* __restrict__ olo) {
    constexpr int V = F / 64;      // 2 or 4
    constexpr int D = F / 4;
    int wid = (blockIdx.x * 256 + threadIdx.x) >> 6;
    int lane = threadIdx.x & 63;
    if (wid >= N_NODES) return;
    int row0 = rowptr[wid], row1 = rowptr[wid + 1];
    int f0 = lane * V;
    int hh = f0 / D;

    float acc[V];
#pragma unroll
    for (int v = 0; v < V; ++v) acc[v] = 0.f;

    for (int base = row0; base < row1; base += 64) {
        int i = base + lane;
        int sv = (i < row1) ? csr_src[i] : 0;
        int cnt = min(64, row1 - base);
        const float* eep = ee + (size_t)base * 4 + hh;
        for (int j = 0; j < cnt; ++j) {
            int s = __shfl(sv, j);
            float w = eep[(size_t)j * 4];
            const float* hp = hfeat + (size_t)s * F + f0;
            if (V == 4) {
                float4 hv = *reinterpret_cast<const float4*>(hp);
                acc[0] = fmaf(w, hv.x, acc[0]);
                acc[1] = fmaf(w, hv.y, acc[1]);
                acc[2] = fmaf(w, hv.z, acc[2]);
                acc[3] = fmaf(w, hv.w, acc[3]);
            } else {
                float2 hv = *reinterpret_cast<const float2*>(hp);
                acc[0] = fmaf(w, hv.x, acc[0]);
                acc[1] = fmaf(w, hv.y, acc[1]);
            }
        }
    }

    float dn = denom[(size_t)wid * 4 + hh];
    float inv = dn > 0.f ? 1.f / dn : 0.f;
    float val[V];
#pragma unroll
    for (int v = 0; v < V; ++v) val[v] = acc[v] * inv + bias[f0 + v];

    if (MODE == 0) {
#pragma unroll
        for (int v = 0; v < V; ++v)
            val[v] = val[v] > 0.f ? val[v] : (__expf(val[v]) - 1.f);
        unsigned short h0 = f2bf(val[0]), h1 = f2bf(val[1]);
        unsigned short l0 = f2bf(val[0] - bf2f(h0)), l1 = f2bf(val[1] - bf2f(h1));
        reinterpret_cast<unsigned int*>(ohi)[(size_t)wid * (F / 2) + lane] =
            (unsigned int)h0 | ((unsigned int)h1 << 16);
        reinterpret_cast<unsigned int*>(olo)[(size_t)wid * (F / 2) + lane] =
            (unsigned int)l0 | ((unsigned int)l1 << 16);
    } else {
#pragma unroll
        for (int v = 0; v < V; ++v) {
            val[v] += __shfl_xor(val[v], 16);
            val[v] += __shfl_xor(val[v], 32);
        }
        if (lane < 16) {
            float4 o = make_float4(val[0] * 0.25f, val[1] * 0.25f, val[2] * 0.25f, val[3] * 0.25f);
            *reinterpret_cast<float4*>(out + (size_t)wid * D + lane * 4) = o;
        }
    }
}

// ---------------------------------------------------------------- launch
extern "C" void kernel_launch(void* const* d_in, const int* in_sizes, int n_in,
                              void* d_out, int out_size, void* d_ws, size_t ws_size,
                              hipStream_t stream) {
    const float* nfeat = (const float*)d_in[0];
    const int* src = (const int*)d_in[1];
    const int* dst = (const int*)d_in[2];
    const float* W0 = (const float*)d_in[3];
    const float* al0 = (const float*)d_in[4];
    const float* ar0 = (const float*)d_in[5];
    const float* b0 = (const float*)d_in[6];
    const float* W1 = (const float*)d_in[7];
    const float* al1 = (const float*)d_in[8];
    const float* ar1 = (const float*)d_in[9];
    const float* b1 = (const float*)d_in[10];
    const float* W2 = (const float*)d_in[11];
    const float* al2 = (const float*)d_in[12];
    const float* ar2 = (const float*)d_in[13];
    const float* b2 = (const float*)d_in[14];
    float* out = (float*)d_out;

    char* w = (char*)d_ws;
    unsigned short* XA_hi = (unsigned short*)w; w += (size_t)N_NODES * 128 * 2;  // 25.6MB
    unsigned short* XA_lo = (unsigned short*)w; w += (size_t)N_NODES * 128 * 2;
    unsigned short* XB_hi = (unsigned short*)w; w += (size_t)N_NODES * 128 * 2;
    unsigned short* XB_lo = (unsigned short*)w; w += (size_t)N_NODES * 128 * 2;
    float* P = (float*)w;      w += (size_t)N_NODES * 128 * 4;                   // 51.2MB
    float* el = (float*)w;     w += (size_t)N_NODES * 4 * 4;
    float* er = (float*)w;     w += (size_t)N_NODES * 4 * 4;
    float* denom = (float*)w;  w += (size_t)N_NODES * 4 * 4;
    int* rowptr = (int*)w;     w += (size_t)(N_NODES + 4) * 4;
    int* deg = (int*)w;        w += (size_t)N_NODES * 4;
    int* bsum = (int*)w;       w += 256 * 4;
    int* csr_src = (int*)w;    w += (size_t)N_EDGES * 4;
    unsigned short* Wt0h = (unsigned short*)w; w += 16384 * 2;
    unsigned short* Wt0l = (unsigned short*)w; w += 16384 * 2;
    unsigned short* Wt1h = (unsigned short*)w; w += 16384 * 2;
    unsigned short* Wt1l = (unsigned short*)w; w += 16384 * 2;
    unsigned short* Wt2h = (unsigned short*)w; w += 32768 * 2;
    unsigned short* Wt2l = (unsigned short*)w; w += 32768 * 2;

    // Aliases (lifetime-checked):
    float* H2  = (float*)XB_hi;   // 102.4MB spans XB_hi+XB_lo+P (all dead at layer-2 GEMM)
    float* ee0 = (float*)XA_hi;   // XA dead after GEMM0 reads it
    float* ee1 = (float*)XB_hi;   // XB dead after GEMM1 reads it
    float* ee2 = (float*)XA_hi;   // XA dead after GEMM2 reads it

    const int nb_scan = (N_NODES + 1023) / 1024;

    // ---- converts
    convert_x_kernel<<<6250, 256, 0, stream>>>(nfeat, XA_hi, XA_lo);
    convert_w_kernel<<<64, 256, 0, stream>>>(W0, Wt0h, Wt0l, 128);
    convert_w_kernel<<<64, 256, 0, stream>>>(W1, Wt1h, Wt1l, 128);
    convert_w_kernel<<<128, 256, 0, stream>>>(W2, Wt2h, Wt2l, 256);

    // ---- CSR build
    hipMemsetAsync(deg, 0, (size_t)N_NODES * 4, stream);
    hist_kernel<<<(N_EDGES + 255) / 256, 256, 0, stream>>>(dst, deg);
    scan_block_kernel<<<nb_scan, 256, 0, stream>>>(deg, rowptr, bsum);
    scan_bsum_kernel<<<1, 128, 0, stream>>>(bsum, nb_scan);
    scan_add_kernel<<<(N_NODES + 256) / 256, 256, 0, stream>>>(rowptr, bsum);
    hipMemsetAsync(deg, 0, (size_t)N_NODES * 4, stream);
    scatter_kernel<<<(N_EDGES + 255) / 256, 256, 0, stream>>>(src, dst, rowptr, deg, csr_src);

    const int sc_blocks = (N_NODES * 4 + 255) / 256;
    const int nw_blocks = (N_NODES + 3) / 4;
    dim3 gg1(782, 1), gg2(782, 2);

    // ---- Layer 0
    mfma_gemm_kernel<<<gg1, 256, 0, stream>>>(XA_hi, XA_lo, Wt0h, Wt0l, P, N_NODES, 128);
    attn_scores_kernel<32><<<sc_blocks, 256, 0, stream>>>(P, al0, ar0, el, er);
    alpha_kernel<<<nw_blocks, 256, 0, stream>>>(el, er, rowptr, csr_src, ee0, denom);
    gather_kernel<128, 0><<<nw_blocks, 256, 0, stream>>>(P, ee0, denom, rowptr, csr_src, b0,
                                                         P, XB_hi, XB_lo);

    // ---- Layer 1
    mfma_gemm_kernel<<<gg1, 256, 0, stream>>>(XB_hi, XB_lo, Wt1h, Wt1l, P, N_NODES, 128);
    attn_scores_kernel<32><<<sc_blocks, 256, 0, stream>>>(P, al1, ar1, el, er);
    alpha_kernel<<<nw_blocks, 256, 0, stream>>>(el, er, rowptr, csr_src, ee1, denom);
    gather_kernel<128, 0><<<nw_blocks, 256, 0, stream>>>(P, ee1, denom, rowptr, csr_src, b1,
                                                         P, XA_hi, XA_lo);

    // ---- Layer 2
    mfma_gemm_kernel<<<gg2, 256, 0, stream>>>(XA_hi, XA_lo, Wt2h, Wt2l, H2, N_NODES, 256);
    attn_scores_kernel<64><<<sc_blocks, 256, 0, stream>>>(H2, al2, ar2, el, er);
    alpha_kernel<<<nw_blocks, 256, 0, stream>>>(el, er, rowptr, csr_src, ee2, denom);
    gather_kernel<256, 1><<<nw_blocks, 256, 0, stream>>>(H2, ee2, denom, rowptr, csr_src, b2,
                                                         out, XB_hi, XB_lo);
}

// Round 4
// 918.753 us; speedup vs baseline: 1.9473x; 1.1626x over previous
//
#include <hip/hip_runtime.h>
#include <hip/hip_bf16.h>
#include <cstddef>
#include <cstdint>

#define N_NODES 100000
#define N_EDGES 1600000

typedef __attribute__((ext_vector_type(8))) short bf16x8;
typedef __attribute__((ext_vector_type(4))) float f32x4;
typedef __attribute__((ext_vector_type(2))) _Float16 half2_t;
typedef __attribute__((ext_vector_type(4))) _Float16 half4_t;

__device__ inline unsigned short f2bf(float x) {
    unsigned int u = __float_as_uint(x);
    unsigned int r = (u + 0x7fffu + ((u >> 16) & 1u)) >> 16;
    return (unsigned short)r;
}
__device__ inline float bf2f(unsigned short b) {
    return __uint_as_float((unsigned int)b << 16);
}
__device__ inline unsigned int packh2(float a, float b) {
    half2_t p = {(_Float16)a, (_Float16)b};
    return __builtin_bit_cast(unsigned int, p);
}

// ---------------------------------------------------------------- CSR build
__global__ void hist_kernel(const int* __restrict__ dst, int* __restrict__ deg) {
    int e = blockIdx.x * 256 + threadIdx.x;
    if (e < N_EDGES) atomicAdd(&deg[dst[e]], 1);
}

__global__ void scan_block_kernel(const int* __restrict__ deg, int* __restrict__ rowptr,
                                  int* __restrict__ bsum) {
    __shared__ int s[256];
    int t = threadIdx.x;
    int base = blockIdx.x * 1024 + t * 4;
    int v[4]; int sum = 0;
#pragma unroll
    for (int j = 0; j < 4; ++j) { v[j] = (base + j < N_NODES) ? deg[base + j] : 0; sum += v[j]; }
    s[t] = sum; __syncthreads();
    for (int off = 1; off < 256; off <<= 1) {
        int x = (t >= off) ? s[t - off] : 0;
        __syncthreads();
        s[t] += x;
        __syncthreads();
    }
    int excl = (t > 0) ? s[t - 1] : 0;
    if (t == 255) bsum[blockIdx.x] = s[255];
    int run = excl;
#pragma unroll
    for (int j = 0; j < 4; ++j) { if (base + j < N_NODES) rowptr[base + j] = run; run += v[j]; }
}

__global__ void scan_bsum_kernel(int* bsum, int nb) {
    __shared__ int s[128];
    int t = threadIdx.x;
    int v = (t < nb) ? bsum[t] : 0;
    s[t] = v; __syncthreads();
    for (int off = 1; off < 128; off <<= 1) {
        int x = (t >= off) ? s[t - off] : 0;
        __syncthreads();
        s[t] += x;
        __syncthreads();
    }
    if (t < nb) bsum[t] = (t > 0) ? s[t - 1] : 0;
}

__global__ void scan_add_kernel(int* __restrict__ rowptr, const int* __restrict__ bsum) {
    int i = blockIdx.x * 256 + threadIdx.x;
    if (i < N_NODES) rowptr[i] += bsum[i >> 10];
    if (i == 0) rowptr[N_NODES] = N_EDGES;
}

__global__ void scatter_kernel(const int* __restrict__ src, const int* __restrict__ dst,
                               const int* __restrict__ rowptr, int* __restrict__ fill,
                               int* __restrict__ csr_src) {
    int e = blockIdx.x * 256 + threadIdx.x;
    if (e < N_EDGES) {
        int d = dst[e];
        int pos = rowptr[d] + atomicAdd(&fill[d], 1);
        csr_src[pos] = src[e];
    }
}

// ---------------------------------------------------------------- fp32 -> bf16 hi/lo converts
__global__ __launch_bounds__(256) void convert_x_kernel(const float* __restrict__ X,
                                                        unsigned short* __restrict__ hi,
                                                        unsigned short* __restrict__ lo) {
    size_t t = blockIdx.x * 256 + threadIdx.x;
    float4 v0 = *reinterpret_cast<const float4*>(X + t * 8);
    float4 v1 = *reinterpret_cast<const float4*>(X + t * 8 + 4);
    float xs[8] = {v0.x, v0.y, v0.z, v0.w, v1.x, v1.y, v1.z, v1.w};
    unsigned int hp[4], lp[4];
#pragma unroll
    for (int j = 0; j < 4; ++j) {
        unsigned short h0 = f2bf(xs[2 * j]), h1 = f2bf(xs[2 * j + 1]);
        unsigned short l0 = f2bf(xs[2 * j] - bf2f(h0));
        unsigned short l1 = f2bf(xs[2 * j + 1] - bf2f(h1));
        hp[j] = (unsigned int)h0 | ((unsigned int)h1 << 16);
        lp[j] = (unsigned int)l0 | ((unsigned int)l1 << 16);
    }
    *reinterpret_cast<uint4*>(hi + t * 8) = make_uint4(hp[0], hp[1], hp[2], hp[3]);
    *reinterpret_cast<uint4*>(lo + t * 8) = make_uint4(lp[0], lp[1], lp[2], lp[3]);
}

__global__ __launch_bounds__(256) void convert_w_kernel(const float* __restrict__ W,
                                                        unsigned short* __restrict__ Wth,
                                                        unsigned short* __restrict__ Wtl,
                                                        int Ncols) {
    int t = blockIdx.x * 256 + threadIdx.x;
    if (t >= 128 * Ncols) return;
    int n = t >> 7, k = t & 127;
    float x = W[(size_t)k * Ncols + n];
    unsigned short h = f2bf(x);
    unsigned short l = f2bf(x - bf2f(h));
    Wth[t] = h;
    Wtl[t] = l;
}

// ---------------------------------------------------------------- MFMA split-bf16 GEMM
__global__ __launch_bounds__(256) void mfma_gemm_kernel(
    const unsigned short* __restrict__ Xhi, const unsigned short* __restrict__ Xlo,
    const unsigned short* __restrict__ Wth, const unsigned short* __restrict__ Wtl,
    float* __restrict__ C, int M, int ldC) {
    __shared__ unsigned short AH[128 * 136];
    __shared__ unsigned short AL[128 * 136];
    const int tid = threadIdx.x;
    const int wave = tid >> 6, lane = tid & 63;
    const int r = lane & 15, kg = lane >> 4;
    const int row0 = blockIdx.x * 128;
    const int col0 = blockIdx.y * 128;

#pragma unroll
    for (int i = 0; i < 16; ++i) {
        int sa = i * 256 + tid;
        int a = sa >> 11;
        int s = sa & 2047;
        int rr = s >> 4;
        int u = s & 15;
        const unsigned short* srcp = (a ? Xlo : Xhi) + (size_t)(row0 + rr) * 128 + u * 8;
        unsigned short* dstp = (a ? AL : AH) + rr * 136 + u * 8;
        *reinterpret_cast<uint4*>(dstp) = *reinterpret_cast<const uint4*>(srcp);
    }
    __syncthreads();

    f32x4 acc[2][8];
#pragma unroll
    for (int rt = 0; rt < 2; ++rt)
#pragma unroll
        for (int ct = 0; ct < 8; ++ct)
            acc[rt][ct] = (f32x4){0.f, 0.f, 0.f, 0.f};

#pragma unroll
    for (int ks = 0; ks < 4; ++ks) {
        bf16x8 bh[8], bl[8];
#pragma unroll
        for (int ct = 0; ct < 8; ++ct) {
            size_t off = (size_t)(col0 + ct * 16 + r) * 128 + ks * 32 + kg * 8;
            bh[ct] = *reinterpret_cast<const bf16x8*>(Wth + off);
            bl[ct] = *reinterpret_cast<const bf16x8*>(Wtl + off);
        }
#pragma unroll
        for (int rt = 0; rt < 2; ++rt) {
            int lrow = wave * 32 + rt * 16 + r;
            bf16x8 ah = *reinterpret_cast<const bf16x8*>(&AH[lrow * 136 + ks * 32 + kg * 8]);
            bf16x8 al = *reinterpret_cast<const bf16x8*>(&AL[lrow * 136 + ks * 32 + kg * 8]);
#pragma unroll
            for (int ct = 0; ct < 8; ++ct) {
                acc[rt][ct] = __builtin_amdgcn_mfma_f32_16x16x32_bf16(ah, bh[ct], acc[rt][ct], 0, 0, 0);
                acc[rt][ct] = __builtin_amdgcn_mfma_f32_16x16x32_bf16(al, bh[ct], acc[rt][ct], 0, 0, 0);
                acc[rt][ct] = __builtin_amdgcn_mfma_f32_16x16x32_bf16(ah, bl[ct], acc[rt][ct], 0, 0, 0);
            }
        }
    }

#pragma unroll
    for (int rt = 0; rt < 2; ++rt) {
#pragma unroll
        for (int j = 0; j < 4; ++j) {
            int grow = row0 + wave * 32 + rt * 16 + kg * 4 + j;
            if (grow < M) {
#pragma unroll
                for (int ct = 0; ct < 8; ++ct)
                    C[(size_t)grow * ldC + col0 + ct * 16 + r] = acc[rt][ct][j];
            }
        }
    }
}

// ---------------------------------------------------------------- el/er dots + fp16 copy
template <int D>
__global__ __launch_bounds__(256) void attn_scores_kernel(
    const float* __restrict__ h, const float* __restrict__ al, const float* __restrict__ ar,
    float* __restrict__ el, float* __restrict__ er, _Float16* __restrict__ Ph) {
    int t = blockIdx.x * 256 + threadIdx.x;
    if (t >= N_NODES * 4) return;
    int n = t >> 2, hh = t & 3;
    const float* hp = h + (size_t)n * (4 * D) + hh * D;
    const float* alp = al + hh * D;
    const float* arp = ar + hh * D;
    unsigned int hw[D / 2];
    float sl = 0.f, sr = 0.f;
#pragma unroll
    for (int d = 0; d < D; d += 4) {
        float4 hv = *reinterpret_cast<const float4*>(hp + d);
        float4 av = *reinterpret_cast<const float4*>(alp + d);
        float4 rv = *reinterpret_cast<const float4*>(arp + d);
        sl += hv.x * av.x + hv.y * av.y + hv.z * av.z + hv.w * av.w;
        sr += hv.x * rv.x + hv.y * rv.y + hv.z * rv.z + hv.w * rv.w;
        hw[d / 2] = packh2(hv.x, hv.y);
        hw[d / 2 + 1] = packh2(hv.z, hv.w);
    }
    el[t] = sl;
    er[t] = sr;
    unsigned int* php = reinterpret_cast<unsigned int*>(Ph + (size_t)n * (4 * D) + hh * D);
#pragma unroll
    for (int i = 0; i < D / 2; i += 4)
        *reinterpret_cast<uint4*>(php + i) = make_uint4(hw[i], hw[i + 1], hw[i + 2], hw[i + 3]);
}

// ---------------------------------------------------------------- softmax weights
__global__ __launch_bounds__(256) void alpha_kernel(
    const float* __restrict__ el, const float* __restrict__ er,
    const int* __restrict__ rowptr, const int* __restrict__ csr_src,
    float* __restrict__ ee, float* __restrict__ denom) {
    int wid = (blockIdx.x * 256 + threadIdx.x) >> 6;
    int lane = threadIdx.x & 63;
    if (wid >= N_NODES) return;
    int row0 = rowptr[wid], row1 = rowptr[wid + 1];
    float4 ern = *reinterpret_cast<const float4*>(er + (size_t)wid * 4);

    float4 mx = make_float4(-INFINITY, -INFINITY, -INFINITY, -INFINITY);
    for (int base = row0; base < row1; base += 64) {
        int i = base + lane;
        if (i < row1) {
            int s = csr_src[i];
            float4 e4 = *reinterpret_cast<const float4*>(el + (size_t)s * 4);
            float4 sc;
            sc.x = e4.x + ern.x; sc.x = sc.x > 0.f ? sc.x : 0.2f * sc.x;
            sc.y = e4.y + ern.y; sc.y = sc.y > 0.f ? sc.y : 0.2f * sc.y;
            sc.z = e4.z + ern.z; sc.z = sc.z > 0.f ? sc.z : 0.2f * sc.z;
            sc.w = e4.w + ern.w; sc.w = sc.w > 0.f ? sc.w : 0.2f * sc.w;
            mx.x = fmaxf(mx.x, sc.x); mx.y = fmaxf(mx.y, sc.y);
            mx.z = fmaxf(mx.z, sc.z); mx.w = fmaxf(mx.w, sc.w);
        }
    }
#pragma unroll
    for (int off = 1; off < 64; off <<= 1) {
        mx.x = fmaxf(mx.x, __shfl_xor(mx.x, off));
        mx.y = fmaxf(mx.y, __shfl_xor(mx.y, off));
        mx.z = fmaxf(mx.z, __shfl_xor(mx.z, off));
        mx.w = fmaxf(mx.w, __shfl_xor(mx.w, off));
    }

    float4 sum = make_float4(0.f, 0.f, 0.f, 0.f);
    for (int base = row0; base < row1; base += 64) {
        int i = base + lane;
        if (i < row1) {
            int s = csr_src[i];
            float4 e4 = *reinterpret_cast<const float4*>(el + (size_t)s * 4);
            float4 sc;
            sc.x = e4.x + ern.x; sc.x = sc.x > 0.f ? sc.x : 0.2f * sc.x;
            sc.y = e4.y + ern.y; sc.y = sc.y > 0.f ? sc.y : 0.2f * sc.y;
            sc.z = e4.z + ern.z; sc.z = sc.z > 0.f ? sc.z : 0.2f * sc.z;
            sc.w = e4.w + ern.w; sc.w = sc.w > 0.f ? sc.w : 0.2f * sc.w;
            float4 e;
            e.x = __expf(sc.x - mx.x); e.y = __expf(sc.y - mx.y);
            e.z = __expf(sc.z - mx.z); e.w = __expf(sc.w - mx.w);
            sum.x += e.x; sum.y += e.y; sum.z += e.z; sum.w += e.w;
            *reinterpret_cast<float4*>(ee + (size_t)i * 4) = e;
        }
    }
#pragma unroll
    for (int off = 1; off < 64; off <<= 1) {
        sum.x += __shfl_xor(sum.x, off);
        sum.y += __shfl_xor(sum.y, off);
        sum.z += __shfl_xor(sum.z, off);
        sum.w += __shfl_xor(sum.w, off);
    }
    if (lane == 0) *reinterpret_cast<float4*>(denom + (size_t)wid * 4) = sum;
}

// ---------------------------------------------------------------- weighted gather (fp16 feats)
// MODE 0: elu -> bf16 hi/lo [N,F].  MODE 1: head-mean -> out[N,F/4] fp32.
template <int F, int MODE>
__global__ __launch_bounds__(256) void gather_kernel(
    const _Float16* __restrict__ hfeat, const float* __restrict__ ee,
    const float* __restrict__ denom, const int* __restrict__ rowptr,
    const int* __restrict__ csr_src, const float* __restrict__ bias,
    float* __restrict__ out, unsigned short* __restrict__ ohi,
    unsigned short* __restrict__ olo) {
    constexpr int V = F / 64;      // 2 or 4
    constexpr int D = F / 4;
    int wid = (blockIdx.x * 256 + threadIdx.x) >> 6;
    int lane = threadIdx.x & 63;
    if (wid >= N_NODES) return;
    int row0 = rowptr[wid], row1 = rowptr[wid + 1];
    int f0 = lane * V;
    int hh = f0 / D;

    float accA[V], accB[V];
#pragma unroll
    for (int v = 0; v < V; ++v) { accA[v] = 0.f; accB[v] = 0.f; }

    for (int base = row0; base < row1; base += 64) {
        int i = base + lane;
        int sv = (i < row1) ? csr_src[i] : 0;
        int cnt = min(64, row1 - base);
        const float* eep = ee + (size_t)base * 4 + hh;
        int j = 0;
        for (; j + 2 <= cnt; j += 2) {
            int s0 = __shfl(sv, j);
            int s1 = __shfl(sv, j + 1);
            float w0 = eep[(size_t)j * 4];
            float w1 = eep[(size_t)(j + 1) * 4];
            if (V == 4) {
                half4_t a = *reinterpret_cast<const half4_t*>(hfeat + (size_t)s0 * F + f0);
                half4_t b = *reinterpret_cast<const half4_t*>(hfeat + (size_t)s1 * F + f0);
                accA[0] = fmaf(w0, (float)a.x, accA[0]); accB[0] = fmaf(w1, (float)b.x, accB[0]);
                accA[1] = fmaf(w0, (float)a.y, accA[1]); accB[1] = fmaf(w1, (float)b.y, accB[1]);
                accA[2] = fmaf(w0, (float)a.z, accA[2]); accB[2] = fmaf(w1, (float)b.z, accB[2]);
                accA[3] = fmaf(w0, (float)a.w, accA[3]); accB[3] = fmaf(w1, (float)b.w, accB[3]);
            } else {
                half2_t a = *reinterpret_cast<const half2_t*>(hfeat + (size_t)s0 * F + f0);
                half2_t b = *reinterpret_cast<const half2_t*>(hfeat + (size_t)s1 * F + f0);
                accA[0] = fmaf(w0, (float)a.x, accA[0]); accB[0] = fmaf(w1, (float)b.x, accB[0]);
                accA[1] = fmaf(w0, (float)a.y, accA[1]); accB[1] = fmaf(w1, (float)b.y, accB[1]);
            }
        }
        if (j < cnt) {
            int s0 = __shfl(sv, j);
            float w0 = eep[(size_t)j * 4];
            if (V == 4) {
                half4_t a = *reinterpret_cast<const half4_t*>(hfeat + (size_t)s0 * F + f0);
                accA[0] = fmaf(w0, (float)a.x, accA[0]);
                accA[1] = fmaf(w0, (float)a.y, accA[1]);
                accA[2] = fmaf(w0, (float)a.z, accA[2]);
                accA[3] = fmaf(w0, (float)a.w, accA[3]);
            } else {
                half2_t a = *reinterpret_cast<const half2_t*>(hfeat + (size_t)s0 * F + f0);
                accA[0] = fmaf(w0, (float)a.x, accA[0]);
                accA[1] = fmaf(w0, (float)a.y, accA[1]);
            }
        }
    }

    float dn = denom[(size_t)wid * 4 + hh];
    float inv = dn > 0.f ? 1.f / dn : 0.f;
    float val[V];
#pragma unroll
    for (int v = 0; v < V; ++v) val[v] = (accA[v] + accB[v]) * inv + bias[f0 + v];

    if (MODE == 0) {
#pragma unroll
        for (int v = 0; v < V; ++v)
            val[v] = val[v] > 0.f ? val[v] : (__expf(val[v]) - 1.f);
        unsigned short h0 = f2bf(val[0]), h1 = f2bf(val[1]);
        unsigned short l0 = f2bf(val[0] - bf2f(h0)), l1 = f2bf(val[1] - bf2f(h1));
        reinterpret_cast<unsigned int*>(ohi)[(size_t)wid * (F / 2) + lane] =
            (unsigned int)h0 | ((unsigned int)h1 << 16);
        reinterpret_cast<unsigned int*>(olo)[(size_t)wid * (F / 2) + lane] =
            (unsigned int)l0 | ((unsigned int)l1 << 16);
    } else {
#pragma unroll
        for (int v = 0; v < V; ++v) {
            val[v] += __shfl_xor(val[v], 16);
            val[v] += __shfl_xor(val[v], 32);
        }
        if (lane < 16) {
            float4 o = make_float4(val[0] * 0.25f, val[1] * 0.25f, val[2] * 0.25f, val[3] * 0.25f);
            *reinterpret_cast<float4*>(out + (size_t)wid * D + lane * 4) = o;
        }
    }
}

// ---------------------------------------------------------------- launch
extern "C" void kernel_launch(void* const* d_in, const int* in_sizes, int n_in,
                              void* d_out, int out_size, void* d_ws, size_t ws_size,
                              hipStream_t stream) {
    const float* nfeat = (const float*)d_in[0];
    const int* src = (const int*)d_in[1];
    const int* dst = (const int*)d_in[2];
    const float* W0 = (const float*)d_in[3];
    const float* al0 = (const float*)d_in[4];
    const float* ar0 = (const float*)d_in[5];
    const float* b0 = (const float*)d_in[6];
    const float* W1 = (const float*)d_in[7];
    const float* al1 = (const float*)d_in[8];
    const float* ar1 = (const float*)d_in[9];
    const float* b1 = (const float*)d_in[10];
    const float* W2 = (const float*)d_in[11];
    const float* al2 = (const float*)d_in[12];
    const float* ar2 = (const float*)d_in[13];
    const float* b2 = (const float*)d_in[14];
    float* out = (float*)d_out;

    char* w = (char*)d_ws;
    unsigned short* XA_hi = (unsigned short*)w; w += (size_t)N_NODES * 128 * 2;  // 25.6MB
    unsigned short* XA_lo = (unsigned short*)w; w += (size_t)N_NODES * 128 * 2;
    unsigned short* XB_hi = (unsigned short*)w; w += (size_t)N_NODES * 128 * 2;
    unsigned short* XB_lo = (unsigned short*)w; w += (size_t)N_NODES * 128 * 2;
    float* P = (float*)w;      w += (size_t)N_NODES * 128 * 4;                   // 51.2MB
    _Float16* Ph01 = (_Float16*)w; w += (size_t)N_NODES * 128 * 2;               // 25.6MB
    float* el = (float*)w;     w += (size_t)N_NODES * 4 * 4;
    float* er = (float*)w;     w += (size_t)N_NODES * 4 * 4;
    float* denom = (float*)w;  w += (size_t)N_NODES * 4 * 4;
    int* rowptr = (int*)w;     w += (size_t)(N_NODES + 4) * 4;
    int* deg = (int*)w;        w += (size_t)N_NODES * 4;
    int* bsum = (int*)w;       w += 256 * 4;
    int* csr_src = (int*)w;    w += (size_t)N_EDGES * 4;
    unsigned short* Wt0h = (unsigned short*)w; w += 16384 * 2;
    unsigned short* Wt0l = (unsigned short*)w; w += 16384 * 2;
    unsigned short* Wt1h = (unsigned short*)w; w += 16384 * 2;
    unsigned short* Wt1l = (unsigned short*)w; w += 16384 * 2;
    unsigned short* Wt2h = (unsigned short*)w; w += 32768 * 2;
    unsigned short* Wt2l = (unsigned short*)w; w += 32768 * 2;

    // Aliases (lifetime-checked):
    float* H2  = (float*)XB_hi;     // 102.4MB over XB_hi+XB_lo+P (dead at layer-2 GEMM)
    _Float16* H2h = (_Float16*)XA_hi; // 51.2MB over XA (dead after layer-2 GEMM reads it)
    float* ee0 = (float*)XA_hi;     // XA dead after GEMM0
    float* ee1 = (float*)XB_hi;     // XB dead after GEMM1
    float* ee2 = (float*)Ph01;      // Ph01 dead after gather1

    const int nb_scan = (N_NODES + 1023) / 1024;

    // ---- converts
    convert_x_kernel<<<6250, 256, 0, stream>>>(nfeat, XA_hi, XA_lo);
    convert_w_kernel<<<64, 256, 0, stream>>>(W0, Wt0h, Wt0l, 128);
    convert_w_kernel<<<64, 256, 0, stream>>>(W1, Wt1h, Wt1l, 128);
    convert_w_kernel<<<128, 256, 0, stream>>>(W2, Wt2h, Wt2l, 256);

    // ---- CSR build
    hipMemsetAsync(deg, 0, (size_t)N_NODES * 4, stream);
    hist_kernel<<<(N_EDGES + 255) / 256, 256, 0, stream>>>(dst, deg);
    scan_block_kernel<<<nb_scan, 256, 0, stream>>>(deg, rowptr, bsum);
    scan_bsum_kernel<<<1, 128, 0, stream>>>(bsum, nb_scan);
    scan_add_kernel<<<(N_NODES + 256) / 256, 256, 0, stream>>>(rowptr, bsum);
    hipMemsetAsync(deg, 0, (size_t)N_NODES * 4, stream);
    scatter_kernel<<<(N_EDGES + 255) / 256, 256, 0, stream>>>(src, dst, rowptr, deg, csr_src);

    const int sc_blocks = (N_NODES * 4 + 255) / 256;
    const int nw_blocks = (N_NODES + 3) / 4;
    dim3 gg1(782, 1), gg2(782, 2);

    // ---- Layer 0
    mfma_gemm_kernel<<<gg1, 256, 0, stream>>>(XA_hi, XA_lo, Wt0h, Wt0l, P, N_NODES, 128);
    attn_scores_kernel<32><<<sc_blocks, 256, 0, stream>>>(P, al0, ar0, el, er, Ph01);
    alpha_kernel<<<nw_blocks, 256, 0, stream>>>(el, er, rowptr, csr_src, ee0, denom);
    gather_kernel<128, 0><<<nw_blocks, 256, 0, stream>>>(Ph01, ee0, denom, rowptr, csr_src, b0,
                                                         nullptr, XB_hi, XB_lo);

    // ---- Layer 1
    mfma_gemm_kernel<<<gg1, 256, 0, stream>>>(XB_hi, XB_lo, Wt1h, Wt1l, P, N_NODES, 128);
    attn_scores_kernel<32><<<sc_blocks, 256, 0, stream>>>(P, al1, ar1, el, er, Ph01);
    alpha_kernel<<<nw_blocks, 256, 0, stream>>>(el, er, rowptr, csr_src, ee1, denom);
    gather_kernel<128, 0><<<nw_blocks, 256, 0, stream>>>(Ph01, ee1, denom, rowptr, csr_src, b1,
                                                         nullptr, XA_hi, XA_lo);

    // ---- Layer 2
    mfma_gemm_kernel<<<gg2, 256, 0, stream>>>(XA_hi, XA_lo, Wt2h, Wt2l, H2, N_NODES, 256);
    attn_scores_kernel<64><<<sc_blocks, 256, 0, stream>>>(H2, al2, ar2, el, er, H2h);
    alpha_kernel<<<nw_blocks, 256, 0, stream>>>(el, er, rowptr, csr_src, ee2, denom);
    gather_kernel<256, 1><<<nw_blocks, 256, 0, stream>>>(H2h, ee2, denom, rowptr, csr_src, b2,
                                                         out, nullptr, nullptr);
}

// Round 5
// 831.719 us; speedup vs baseline: 2.1511x; 1.1046x over previous
//
#include <hip/hip_runtime.h>
#include <hip/hip_bf16.h>
#include <cstddef>
#include <cstdint>

#define N_NODES 100000
#define N_EDGES 1600000

typedef __attribute__((ext_vector_type(8))) short bf16x8;
typedef __attribute__((ext_vector_type(4))) float f32x4;
typedef __attribute__((ext_vector_type(2))) _Float16 half2_t;
typedef __attribute__((ext_vector_type(4))) _Float16 half4_t;

__device__ inline unsigned short f2bf(float x) {
    unsigned int u = __float_as_uint(x);
    unsigned int r = (u + 0x7fffu + ((u >> 16) & 1u)) >> 16;
    return (unsigned short)r;
}
__device__ inline float bf2f(unsigned short b) {
    return __uint_as_float((unsigned int)b << 16);
}
__device__ inline unsigned short f2h_bits(float x) {
    _Float16 h = (_Float16)x;
    return __builtin_bit_cast(unsigned short, h);
}

// ---------------------------------------------------------------- CSR build
__global__ void hist_kernel(const int* __restrict__ dst, int* __restrict__ deg) {
    int e = blockIdx.x * 256 + threadIdx.x;
    if (e < N_EDGES) atomicAdd(&deg[dst[e]], 1);
}

__global__ void scan_block_kernel(const int* __restrict__ deg, int* __restrict__ rowptr,
                                  int* __restrict__ bsum) {
    __shared__ int s[256];
    int t = threadIdx.x;
    int base = blockIdx.x * 1024 + t * 4;
    int v[4]; int sum = 0;
#pragma unroll
    for (int j = 0; j < 4; ++j) { v[j] = (base + j < N_NODES) ? deg[base + j] : 0; sum += v[j]; }
    s[t] = sum; __syncthreads();
    for (int off = 1; off < 256; off <<= 1) {
        int x = (t >= off) ? s[t - off] : 0;
        __syncthreads();
        s[t] += x;
        __syncthreads();
    }
    int excl = (t > 0) ? s[t - 1] : 0;
    if (t == 255) bsum[blockIdx.x] = s[255];
    int run = excl;
#pragma unroll
    for (int j = 0; j < 4; ++j) { if (base + j < N_NODES) rowptr[base + j] = run; run += v[j]; }
}

__global__ void scan_bsum_kernel(int* bsum, int nb) {
    __shared__ int s[128];
    int t = threadIdx.x;
    int v = (t < nb) ? bsum[t] : 0;
    s[t] = v; __syncthreads();
    for (int off = 1; off < 128; off <<= 1) {
        int x = (t >= off) ? s[t - off] : 0;
        __syncthreads();
        s[t] += x;
        __syncthreads();
    }
    if (t < nb) bsum[t] = (t > 0) ? s[t - 1] : 0;
}

__global__ void scan_add_kernel(int* __restrict__ rowptr, const int* __restrict__ bsum) {
    int i = blockIdx.x * 256 + threadIdx.x;
    if (i < N_NODES) rowptr[i] += bsum[i >> 10];
    if (i == 0) rowptr[N_NODES] = N_EDGES;
}

__global__ void scatter_kernel(const int* __restrict__ src, const int* __restrict__ dst,
                               const int* __restrict__ rowptr, int* __restrict__ fill,
                               int* __restrict__ csr_src) {
    int e = blockIdx.x * 256 + threadIdx.x;
    if (e < N_EDGES) {
        int d = dst[e];
        int pos = rowptr[d] + atomicAdd(&fill[d], 1);
        csr_src[pos] = src[e];
    }
}

// ---------------------------------------------------------------- fp32 -> bf16 hi/lo converts
__global__ __launch_bounds__(256) void convert_x_kernel(const float* __restrict__ X,
                                                        unsigned short* __restrict__ hi,
                                                        unsigned short* __restrict__ lo) {
    size_t t = blockIdx.x * 256 + threadIdx.x;
    float4 v0 = *reinterpret_cast<const float4*>(X + t * 8);
    float4 v1 = *reinterpret_cast<const float4*>(X + t * 8 + 4);
    float xs[8] = {v0.x, v0.y, v0.z, v0.w, v1.x, v1.y, v1.z, v1.w};
    unsigned int hp[4], lp[4];
#pragma unroll
    for (int j = 0; j < 4; ++j) {
        unsigned short h0 = f2bf(xs[2 * j]), h1 = f2bf(xs[2 * j + 1]);
        unsigned short l0 = f2bf(xs[2 * j] - bf2f(h0));
        unsigned short l1 = f2bf(xs[2 * j + 1] - bf2f(h1));
        hp[j] = (unsigned int)h0 | ((unsigned int)h1 << 16);
        lp[j] = (unsigned int)l0 | ((unsigned int)l1 << 16);
    }
    *reinterpret_cast<uint4*>(hi + t * 8) = make_uint4(hp[0], hp[1], hp[2], hp[3]);
    *reinterpret_cast<uint4*>(lo + t * 8) = make_uint4(lp[0], lp[1], lp[2], lp[3]);
}

__global__ __launch_bounds__(256) void convert_w_kernel(const float* __restrict__ W,
                                                        unsigned short* __restrict__ Wth,
                                                        unsigned short* __restrict__ Wtl,
                                                        int Ncols) {
    int t = blockIdx.x * 256 + threadIdx.x;
    if (t >= 128 * Ncols) return;
    int n = t >> 7, k = t & 127;
    float x = W[(size_t)k * Ncols + n];
    unsigned short h = f2bf(x);
    unsigned short l = f2bf(x - bf2f(h));
    Wth[t] = h;
    Wtl[t] = l;
}

// ---------------------------------------------------------------- MFMA split-bf16 GEMM
// Fused epilogue: el/er (exact, from fp32 acc, 16-lane butterfly) + fp16 h via LDS repack.
// No fp32 C is materialized.  DHEAD = per-head width (32 or 64).
template <int DHEAD>
__global__ __launch_bounds__(256) void mfma_gemm_kernel(
    const unsigned short* __restrict__ Xhi, const unsigned short* __restrict__ Xlo,
    const unsigned short* __restrict__ Wth, const unsigned short* __restrict__ Wtl,
    float* __restrict__ el, float* __restrict__ er, _Float16* __restrict__ Hh,
    int M, int ldH, const float* __restrict__ alv, const float* __restrict__ arv) {
    __shared__ unsigned short AH[128 * 136];
    __shared__ unsigned short AL[128 * 136];
    const int tid = threadIdx.x;
    const int wave = tid >> 6, lane = tid & 63;
    const int r = lane & 15, kg = lane >> 4;
    const int row0 = blockIdx.x * 128;
    const int col0 = blockIdx.y * 128;

#pragma unroll
    for (int i = 0; i < 16; ++i) {
        int sa = i * 256 + tid;
        int a = sa >> 11;
        int s = sa & 2047;
        int rr = s >> 4;
        int u = s & 15;
        const unsigned short* srcp = (a ? Xlo : Xhi) + (size_t)(row0 + rr) * 128 + u * 8;
        unsigned short* dstp = (a ? AL : AH) + rr * 136 + u * 8;
        *reinterpret_cast<uint4*>(dstp) = *reinterpret_cast<const uint4*>(srcp);
    }
    __syncthreads();

    f32x4 acc[2][8];
#pragma unroll
    for (int rt = 0; rt < 2; ++rt)
#pragma unroll
        for (int ct = 0; ct < 8; ++ct)
            acc[rt][ct] = (f32x4){0.f, 0.f, 0.f, 0.f};

#pragma unroll
    for (int ks = 0; ks < 4; ++ks) {
        bf16x8 bh[8], bl[8];
#pragma unroll
        for (int ct = 0; ct < 8; ++ct) {
            size_t off = (size_t)(col0 + ct * 16 + r) * 128 + ks * 32 + kg * 8;
            bh[ct] = *reinterpret_cast<const bf16x8*>(Wth + off);
            bl[ct] = *reinterpret_cast<const bf16x8*>(Wtl + off);
        }
#pragma unroll
        for (int rt = 0; rt < 2; ++rt) {
            int lrow = wave * 32 + rt * 16 + r;
            bf16x8 ah = *reinterpret_cast<const bf16x8*>(&AH[lrow * 136 + ks * 32 + kg * 8]);
            bf16x8 al8 = *reinterpret_cast<const bf16x8*>(&AL[lrow * 136 + ks * 32 + kg * 8]);
#pragma unroll
            for (int ct = 0; ct < 8; ++ct) {
                acc[rt][ct] = __builtin_amdgcn_mfma_f32_16x16x32_bf16(ah, bh[ct], acc[rt][ct], 0, 0, 0);
                acc[rt][ct] = __builtin_amdgcn_mfma_f32_16x16x32_bf16(al8, bh[ct], acc[rt][ct], 0, 0, 0);
                acc[rt][ct] = __builtin_amdgcn_mfma_f32_16x16x32_bf16(ah, bl[ct], acc[rt][ct], 0, 0, 0);
            }
        }
    }

    // ---- epilogue 1: el/er from fp32 acc.  head(col) = col/DHEAD; cols of a
    // head live across ct (in-thread) and r (16 lanes) -> butterfly over r.
    constexpr int CTH = DHEAD / 16;   // ct-blocks per head
    constexpr int HB = 8 / CTH;       // heads per 128-col block
    float als[8], ars[8];
#pragma unroll
    for (int ct = 0; ct < 8; ++ct) {
        als[ct] = alv[col0 + ct * 16 + r];
        ars[ct] = arv[col0 + ct * 16 + r];
    }
    f32x4 pel[2][HB], per_[2][HB];
#pragma unroll
    for (int rt = 0; rt < 2; ++rt)
#pragma unroll
        for (int hl = 0; hl < HB; ++hl) {
            pel[rt][hl] = (f32x4){0.f, 0.f, 0.f, 0.f};
            per_[rt][hl] = (f32x4){0.f, 0.f, 0.f, 0.f};
        }
#pragma unroll
    for (int rt = 0; rt < 2; ++rt)
#pragma unroll
        for (int ct = 0; ct < 8; ++ct) {
            pel[rt][ct / CTH] += acc[rt][ct] * als[ct];
            per_[rt][ct / CTH] += acc[rt][ct] * ars[ct];
        }
#pragma unroll
    for (int off = 1; off < 16; off <<= 1) {
#pragma unroll
        for (int rt = 0; rt < 2; ++rt)
#pragma unroll
            for (int hl = 0; hl < HB; ++hl)
#pragma unroll
                for (int j = 0; j < 4; ++j) {
                    pel[rt][hl][j] += __shfl_xor(pel[rt][hl][j], off);
                    per_[rt][hl][j] += __shfl_xor(per_[rt][hl][j], off);
                }
    }
#pragma unroll
    for (int hl = 0; hl < HB; ++hl) {
        if (r == hl) {
            int hg = col0 / DHEAD + hl;
#pragma unroll
            for (int rt = 0; rt < 2; ++rt)
#pragma unroll
                for (int j = 0; j < 4; ++j) {
                    int grow = row0 + wave * 32 + rt * 16 + kg * 4 + j;
                    if (grow < M) {
                        el[(size_t)grow * 4 + hg] = pel[rt][hl][j];
                        er[(size_t)grow * 4 + hg] = per_[rt][hl][j];
                    }
                }
        }
    }

    // ---- epilogue 2: fp16 h, repacked via LDS (reuse AH) for coalesced stores
    __syncthreads();
#pragma unroll
    for (int rt = 0; rt < 2; ++rt)
#pragma unroll
        for (int ct = 0; ct < 8; ++ct)
#pragma unroll
            for (int j = 0; j < 4; ++j) {
                int lrow = wave * 32 + rt * 16 + kg * 4 + j;
                AH[lrow * 136 + ct * 16 + r] = f2h_bits(acc[rt][ct][j]);
            }
    __syncthreads();
#pragma unroll
    for (int it = 0; it < 8; ++it) {
        int idx = it * 256 + tid;
        int rr = idx >> 4;
        int c8 = idx & 15;
        int grow = row0 + rr;
        if (grow < M)
            *reinterpret_cast<uint4*>(Hh + (size_t)grow * ldH + col0 + c8 * 8) =
                *reinterpret_cast<const uint4*>(&AH[rr * 136 + c8 * 8]);
    }
}

// ---------------------------------------------------------------- softmax weights
__global__ __launch_bounds__(256) void alpha_kernel(
    const float* __restrict__ el, const float* __restrict__ er,
    const int* __restrict__ rowptr, const int* __restrict__ csr_src,
    float* __restrict__ ee, float* __restrict__ denom) {
    int wid = (blockIdx.x * 256 + threadIdx.x) >> 6;
    int lane = threadIdx.x & 63;
    if (wid >= N_NODES) return;
    int row0 = rowptr[wid], row1 = rowptr[wid + 1];
    float4 ern = *reinterpret_cast<const float4*>(er + (size_t)wid * 4);

    float4 mx = make_float4(-INFINITY, -INFINITY, -INFINITY, -INFINITY);
    for (int base = row0; base < row1; base += 64) {
        int i = base + lane;
        if (i < row1) {
            int s = csr_src[i];
            float4 e4 = *reinterpret_cast<const float4*>(el + (size_t)s * 4);
            float4 sc;
            sc.x = e4.x + ern.x; sc.x = sc.x > 0.f ? sc.x : 0.2f * sc.x;
            sc.y = e4.y + ern.y; sc.y = sc.y > 0.f ? sc.y : 0.2f * sc.y;
            sc.z = e4.z + ern.z; sc.z = sc.z > 0.f ? sc.z : 0.2f * sc.z;
            sc.w = e4.w + ern.w; sc.w = sc.w > 0.f ? sc.w : 0.2f * sc.w;
            mx.x = fmaxf(mx.x, sc.x); mx.y = fmaxf(mx.y, sc.y);
            mx.z = fmaxf(mx.z, sc.z); mx.w = fmaxf(mx.w, sc.w);
        }
    }
#pragma unroll
    for (int off = 1; off < 64; off <<= 1) {
        mx.x = fmaxf(mx.x, __shfl_xor(mx.x, off));
        mx.y = fmaxf(mx.y, __shfl_xor(mx.y, off));
        mx.z = fmaxf(mx.z, __shfl_xor(mx.z, off));
        mx.w = fmaxf(mx.w, __shfl_xor(mx.w, off));
    }

    float4 sum = make_float4(0.f, 0.f, 0.f, 0.f);
    for (int base = row0; base < row1; base += 64) {
        int i = base + lane;
        if (i < row1) {
            int s = csr_src[i];
            float4 e4 = *reinterpret_cast<const float4*>(el + (size_t)s * 4);
            float4 sc;
            sc.x = e4.x + ern.x; sc.x = sc.x > 0.f ? sc.x : 0.2f * sc.x;
            sc.y = e4.y + ern.y; sc.y = sc.y > 0.f ? sc.y : 0.2f * sc.y;
            sc.z = e4.z + ern.z; sc.z = sc.z > 0.f ? sc.z : 0.2f * sc.z;
            sc.w = e4.w + ern.w; sc.w = sc.w > 0.f ? sc.w : 0.2f * sc.w;
            float4 e;
            e.x = __expf(sc.x - mx.x); e.y = __expf(sc.y - mx.y);
            e.z = __expf(sc.z - mx.z); e.w = __expf(sc.w - mx.w);
            sum.x += e.x; sum.y += e.y; sum.z += e.z; sum.w += e.w;
            *reinterpret_cast<float4*>(ee + (size_t)i * 4) = e;
        }
    }
#pragma unroll
    for (int off = 1; off < 64; off <<= 1) {
        sum.x += __shfl_xor(sum.x, off);
        sum.y += __shfl_xor(sum.y, off);
        sum.z += __shfl_xor(sum.z, off);
        sum.w += __shfl_xor(sum.w, off);
    }
    if (lane == 0) *reinterpret_cast<float4*>(denom + (size_t)wid * 4) = sum;
}

// ---------------------------------------------------------------- weighted gather (fp16 feats)
// 4 independent accumulator chains for MLP.  MODE 0: elu -> bf16 hi/lo.
// MODE 1: head-mean -> out[N,F/4] fp32.
template <int F, int MODE>
__global__ __launch_bounds__(256) void gather_kernel(
    const _Float16* __restrict__ hfeat, const float* __restrict__ ee,
    const float* __restrict__ denom, const int* __restrict__ rowptr,
    const int* __restrict__ csr_src, const float* __restrict__ bias,
    float* __restrict__ out, unsigned short* __restrict__ ohi,
    unsigned short* __restrict__ olo) {
    constexpr int V = F / 64;      // 2 or 4
    constexpr int D = F / 4;
    int wid = (blockIdx.x * 256 + threadIdx.x) >> 6;
    int lane = threadIdx.x & 63;
    if (wid >= N_NODES) return;
    int row0 = rowptr[wid], row1 = rowptr[wid + 1];
    int f0 = lane * V;
    int hh = f0 / D;

    float ac0[V], ac1[V], ac2[V], ac3[V];
#pragma unroll
    for (int v = 0; v < V; ++v) { ac0[v] = 0.f; ac1[v] = 0.f; ac2[v] = 0.f; ac3[v] = 0.f; }

    for (int base = row0; base < row1; base += 64) {
        int i = base + lane;
        int sv = (i < row1) ? csr_src[i] : 0;
        int cnt = min(64, row1 - base);
        const float* eep = ee + (size_t)base * 4 + hh;
        int j = 0;
        for (; j + 4 <= cnt; j += 4) {
            int s0 = __shfl(sv, j), s1 = __shfl(sv, j + 1);
            int s2 = __shfl(sv, j + 2), s3 = __shfl(sv, j + 3);
            float w0 = eep[(size_t)(j + 0) * 4], w1 = eep[(size_t)(j + 1) * 4];
            float w2 = eep[(size_t)(j + 2) * 4], w3 = eep[(size_t)(j + 3) * 4];
            if (V == 4) {
                half4_t a = *reinterpret_cast<const half4_t*>(hfeat + (size_t)s0 * F + f0);
                half4_t b = *reinterpret_cast<const half4_t*>(hfeat + (size_t)s1 * F + f0);
                half4_t c = *reinterpret_cast<const half4_t*>(hfeat + (size_t)s2 * F + f0);
                half4_t d = *reinterpret_cast<const half4_t*>(hfeat + (size_t)s3 * F + f0);
#pragma unroll
                for (int v = 0; v < V; ++v) {
                    ac0[v] = fmaf(w0, (float)a[v], ac0[v]);
                    ac1[v] = fmaf(w1, (float)b[v], ac1[v]);
                    ac2[v] = fmaf(w2, (float)c[v], ac2[v]);
                    ac3[v] = fmaf(w3, (float)d[v], ac3[v]);
                }
            } else {
                half2_t a = *reinterpret_cast<const half2_t*>(hfeat + (size_t)s0 * F + f0);
                half2_t b = *reinterpret_cast<const half2_t*>(hfeat + (size_t)s1 * F + f0);
                half2_t c = *reinterpret_cast<const half2_t*>(hfeat + (size_t)s2 * F + f0);
                half2_t d = *reinterpret_cast<const half2_t*>(hfeat + (size_t)s3 * F + f0);
#pragma unroll
                for (int v = 0; v < V; ++v) {
                    ac0[v] = fmaf(w0, (float)a[v], ac0[v]);
                    ac1[v] = fmaf(w1, (float)b[v], ac1[v]);
                    ac2[v] = fmaf(w2, (float)c[v], ac2[v]);
                    ac3[v] = fmaf(w3, (float)d[v], ac3[v]);
                }
            }
        }
        for (; j < cnt; ++j) {
            int s0 = __shfl(sv, j);
            float w0 = eep[(size_t)j * 4];
            if (V == 4) {
                half4_t a = *reinterpret_cast<const half4_t*>(hfeat + (size_t)s0 * F + f0);
#pragma unroll
                for (int v = 0; v < V; ++v) ac0[v] = fmaf(w0, (float)a[v], ac0[v]);
            } else {
                half2_t a = *reinterpret_cast<const half2_t*>(hfeat + (size_t)s0 * F + f0);
#pragma unroll
                for (int v = 0; v < V; ++v) ac0[v] = fmaf(w0, (float)a[v], ac0[v]);
            }
        }
    }

    float dn = denom[(size_t)wid * 4 + hh];
    float inv = dn > 0.f ? 1.f / dn : 0.f;
    float val[V];
#pragma unroll
    for (int v = 0; v < V; ++v)
        val[v] = ((ac0[v] + ac1[v]) + (ac2[v] + ac3[v])) * inv + bias[f0 + v];

    if (MODE == 0) {
#pragma unroll
        for (int v = 0; v < V; ++v)
            val[v] = val[v] > 0.f ? val[v] : (__expf(val[v]) - 1.f);
        unsigned short h0 = f2bf(val[0]), h1 = f2bf(val[1]);
        unsigned short l0 = f2bf(val[0] - bf2f(h0)), l1 = f2bf(val[1] - bf2f(h1));
        reinterpret_cast<unsigned int*>(ohi)[(size_t)wid * (F / 2) + lane] =
            (unsigned int)h0 | ((unsigned int)h1 << 16);
        reinterpret_cast<unsigned int*>(olo)[(size_t)wid * (F / 2) + lane] =
            (unsigned int)l0 | ((unsigned int)l1 << 16);
    } else {
#pragma unroll
        for (int v = 0; v < V; ++v) {
            val[v] += __shfl_xor(val[v], 16);
            val[v] += __shfl_xor(val[v], 32);
        }
        if (lane < 16) {
            float4 o = make_float4(val[0] * 0.25f, val[1] * 0.25f, val[2] * 0.25f, val[3] * 0.25f);
            *reinterpret_cast<float4*>(out + (size_t)wid * D + lane * 4) = o;
        }
    }
}

// ---------------------------------------------------------------- launch
extern "C" void kernel_launch(void* const* d_in, const int* in_sizes, int n_in,
                              void* d_out, int out_size, void* d_ws, size_t ws_size,
                              hipStream_t stream) {
    const float* nfeat = (const float*)d_in[0];
    const int* src = (const int*)d_in[1];
    const int* dst = (const int*)d_in[2];
    const float* W0 = (const float*)d_in[3];
    const float* al0 = (const float*)d_in[4];
    const float* ar0 = (const float*)d_in[5];
    const float* b0 = (const float*)d_in[6];
    const float* W1 = (const float*)d_in[7];
    const float* al1 = (const float*)d_in[8];
    const float* ar1 = (const float*)d_in[9];
    const float* b1 = (const float*)d_in[10];
    const float* W2 = (const float*)d_in[11];
    const float* al2 = (const float*)d_in[12];
    const float* ar2 = (const float*)d_in[13];
    const float* b2 = (const float*)d_in[14];
    float* out = (float*)d_out;

    char* w = (char*)d_ws;
    unsigned short* XA_hi = (unsigned short*)w; w += (size_t)N_NODES * 128 * 2;  // 25.6MB
    unsigned short* XA_lo = (unsigned short*)w; w += (size_t)N_NODES * 128 * 2;
    unsigned short* XB_hi = (unsigned short*)w; w += (size_t)N_NODES * 128 * 2;
    unsigned short* XB_lo = (unsigned short*)w; w += (size_t)N_NODES * 128 * 2;
    _Float16* Ph01 = (_Float16*)w; w += (size_t)N_NODES * 128 * 2;               // 25.6MB
    float* el = (float*)w;     w += (size_t)N_NODES * 4 * 4;
    float* er = (float*)w;     w += (size_t)N_NODES * 4 * 4;
    float* denom = (float*)w;  w += (size_t)N_NODES * 4 * 4;
    int* rowptr = (int*)w;     w += (size_t)(N_NODES + 4) * 4;
    int* deg = (int*)w;        w += (size_t)N_NODES * 4;
    int* bsum = (int*)w;       w += 256 * 4;
    int* csr_src = (int*)w;    w += (size_t)N_EDGES * 4;
    unsigned short* Wt0h = (unsigned short*)w; w += 16384 * 2;
    unsigned short* Wt0l = (unsigned short*)w; w += 16384 * 2;
    unsigned short* Wt1h = (unsigned short*)w; w += 16384 * 2;
    unsigned short* Wt1l = (unsigned short*)w; w += 16384 * 2;
    unsigned short* Wt2h = (unsigned short*)w; w += 32768 * 2;
    unsigned short* Wt2l = (unsigned short*)w; w += 32768 * 2;

    // Aliases (lifetime-checked):
    float* ee0 = (float*)XA_hi;       // XA dead after GEMM0 reads it
    float* ee1 = (float*)XB_hi;       // XB dead after GEMM1 reads it
    _Float16* H2h = (_Float16*)XB_hi; // 51.2MB spans XB_hi+XB_lo (dead at GEMM2)
    float* ee2 = (float*)Ph01;        // Ph01 dead after gather1

    const int nb_scan = (N_NODES + 1023) / 1024;

    // ---- converts
    convert_x_kernel<<<6250, 256, 0, stream>>>(nfeat, XA_hi, XA_lo);
    convert_w_kernel<<<64, 256, 0, stream>>>(W0, Wt0h, Wt0l, 128);
    convert_w_kernel<<<64, 256, 0, stream>>>(W1, Wt1h, Wt1l, 128);
    convert_w_kernel<<<128, 256, 0, stream>>>(W2, Wt2h, Wt2l, 256);

    // ---- CSR build
    hipMemsetAsync(deg, 0, (size_t)N_NODES * 4, stream);
    hist_kernel<<<(N_EDGES + 255) / 256, 256, 0, stream>>>(dst, deg);
    scan_block_kernel<<<nb_scan, 256, 0, stream>>>(deg, rowptr, bsum);
    scan_bsum_kernel<<<1, 128, 0, stream>>>(bsum, nb_scan);
    scan_add_kernel<<<(N_NODES + 256) / 256, 256, 0, stream>>>(rowptr, bsum);
    hipMemsetAsync(deg, 0, (size_t)N_NODES * 4, stream);
    scatter_kernel<<<(N_EDGES + 255) / 256, 256, 0, stream>>>(src, dst, rowptr, deg, csr_src);

    const int nw_blocks = (N_NODES + 3) / 4;
    dim3 gg1(782, 1), gg2(782, 2);

    // ---- Layer 0 (GEMM fuses el/er + fp16 h)
    mfma_gemm_kernel<32><<<gg1, 256, 0, stream>>>(XA_hi, XA_lo, Wt0h, Wt0l,
                                                  el, er, Ph01, N_NODES, 128, al0, ar0);
    alpha_kernel<<<nw_blocks, 256, 0, stream>>>(el, er, rowptr, csr_src, ee0, denom);
    gather_kernel<128, 0><<<nw_blocks, 256, 0, stream>>>(Ph01, ee0, denom, rowptr, csr_src, b0,
                                                         nullptr, XB_hi, XB_lo);

    // ---- Layer 1
    mfma_gemm_kernel<32><<<gg1, 256, 0, stream>>>(XB_hi, XB_lo, Wt1h, Wt1l,
                                                  el, er, Ph01, N_NODES, 128, al1, ar1);
    alpha_kernel<<<nw_blocks, 256, 0, stream>>>(el, er, rowptr, csr_src, ee1, denom);
    gather_kernel<128, 0><<<nw_blocks, 256, 0, stream>>>(Ph01, ee1, denom, rowptr, csr_src, b1,
                                                         nullptr, XA_hi, XA_lo);

    // ---- Layer 2
    mfma_gemm_kernel<64><<<gg2, 256, 0, stream>>>(XA_hi, XA_lo, Wt2h, Wt2l,
                                                  el, er, H2h, N_NODES, 256, al2, ar2);
    alpha_kernel<<<nw_blocks, 256, 0, stream>>>(el, er, rowptr, csr_src, ee2, denom);
    gather_kernel<256, 1><<<nw_blocks, 256, 0, stream>>>(H2h, ee2, denom, rowptr, csr_src, b2,
                                                         out, nullptr, nullptr);
}

// Round 6
// 814.781 us; speedup vs baseline: 2.1958x; 1.0208x over previous
//
#include <hip/hip_runtime.h>
#include <hip/hip_bf16.h>
#include <cstddef>
#include <cstdint>

#define N_NODES 100000
#define N_EDGES 1600000
#define NPASS 8

typedef __attribute__((ext_vector_type(8))) short bf16x8;
typedef __attribute__((ext_vector_type(4))) float f32x4;
typedef __attribute__((ext_vector_type(2))) _Float16 half2_t;
typedef __attribute__((ext_vector_type(4))) _Float16 half4_t;

__device__ inline unsigned short f2bf(float x) {
    unsigned int u = __float_as_uint(x);
    unsigned int r = (u + 0x7fffu + ((u >> 16) & 1u)) >> 16;
    return (unsigned short)r;
}
__device__ inline float bf2f(unsigned short b) {
    return __uint_as_float((unsigned int)b << 16);
}
__device__ inline unsigned short f2h_bits(float x) {
    _Float16 h = (_Float16)x;
    return __builtin_bit_cast(unsigned short, h);
}

// ---------------------------------------------------------------- CSR build
__global__ void hist_kernel(const int* __restrict__ dst, int* __restrict__ deg) {
    int e = blockIdx.x * 256 + threadIdx.x;
    if (e < N_EDGES) atomicAdd(&deg[dst[e]], 1);
}

__global__ void scan_block_kernel(const int* __restrict__ deg, int* __restrict__ rowptr,
                                  int* __restrict__ bsum) {
    __shared__ int s[256];
    int t = threadIdx.x;
    int base = blockIdx.x * 1024 + t * 4;
    int v[4]; int sum = 0;
#pragma unroll
    for (int j = 0; j < 4; ++j) { v[j] = (base + j < N_NODES) ? deg[base + j] : 0; sum += v[j]; }
    s[t] = sum; __syncthreads();
    for (int off = 1; off < 256; off <<= 1) {
        int x = (t >= off) ? s[t - off] : 0;
        __syncthreads();
        s[t] += x;
        __syncthreads();
    }
    int excl = (t > 0) ? s[t - 1] : 0;
    if (t == 255) bsum[blockIdx.x] = s[255];
    int run = excl;
#pragma unroll
    for (int j = 0; j < 4; ++j) { if (base + j < N_NODES) rowptr[base + j] = run; run += v[j]; }
}

__global__ void scan_bsum_kernel(int* bsum, int nb) {
    __shared__ int s[128];
    int t = threadIdx.x;
    int v = (t < nb) ? bsum[t] : 0;
    s[t] = v; __syncthreads();
    for (int off = 1; off < 128; off <<= 1) {
        int x = (t >= off) ? s[t - off] : 0;
        __syncthreads();
        s[t] += x;
        __syncthreads();
    }
    if (t < nb) bsum[t] = (t > 0) ? s[t - 1] : 0;
}

__global__ void scan_add_kernel(int* __restrict__ rowptr, const int* __restrict__ bsum) {
    int i = blockIdx.x * 256 + threadIdx.x;
    if (i < N_NODES) rowptr[i] += bsum[i >> 10];
    if (i == 0) rowptr[N_NODES] = N_EDGES;
}

// Bucketed scatter: only edges whose dst is in [lo,hi) are placed. The write
// window (csr slab + fill slice) is L2-resident -> no line-level write
// amplification to HBM.
__global__ __launch_bounds__(256) void scatter_pass_kernel(
    const int* __restrict__ src, const int* __restrict__ dst,
    const int* __restrict__ rowptr, int* __restrict__ fill,
    int* __restrict__ csr_src, int lo, int hi) {
    int e = blockIdx.x * 256 + threadIdx.x;
    if (e >= N_EDGES) return;
    int d = dst[e];
    if (d >= lo && d < hi) {
        int pos = rowptr[d] + atomicAdd(&fill[d], 1);
        csr_src[pos] = src[e];
    }
}

// ---------------------------------------------------------------- W converts
__global__ __launch_bounds__(256) void convert_w_kernel(const float* __restrict__ W,
                                                        unsigned short* __restrict__ Wth,
                                                        unsigned short* __restrict__ Wtl,
                                                        int Ncols) {
    int t = blockIdx.x * 256 + threadIdx.x;
    if (t >= 128 * Ncols) return;
    int n = t >> 7, k = t & 127;
    float x = W[(size_t)k * Ncols + n];
    unsigned short h = f2bf(x);
    unsigned short l = f2bf(x - bf2f(h));
    Wth[t] = h;
    Wtl[t] = l;
}

// ---------------------------------------------------------------- MFMA split-bf16 GEMM
// FP32IN: stage raw fp32 X and split to bf16 hi/lo during staging (layer 0).
// Fused epilogue: el/er from fp32 acc (16-lane butterfly) + fp16 h via LDS repack.
template <int DHEAD, bool FP32IN>
__global__ __launch_bounds__(256) void mfma_gemm_kernel(
    const unsigned short* __restrict__ Xhi, const unsigned short* __restrict__ Xlo,
    const float* __restrict__ Xf,
    const unsigned short* __restrict__ Wth, const unsigned short* __restrict__ Wtl,
    float* __restrict__ el, float* __restrict__ er, _Float16* __restrict__ Hh,
    int M, int ldH, const float* __restrict__ alv, const float* __restrict__ arv) {
    __shared__ unsigned short AH[128 * 136];
    __shared__ unsigned short AL[128 * 136];
    const int tid = threadIdx.x;
    const int wave = tid >> 6, lane = tid & 63;
    const int r = lane & 15, kg = lane >> 4;
    const int row0 = blockIdx.x * 128;
    const int col0 = blockIdx.y * 128;

    if constexpr (FP32IN) {
#pragma unroll
        for (int i = 0; i < 16; ++i) {
            int idx = i * 256 + tid;          // 4096 float4 chunks
            int rr = idx >> 5;                // row 0..127
            int u = idx & 31;                 // float4 within row
            int grow = row0 + rr;
            if (grow > M - 1) grow = M - 1;   // input buffer: no overread
            float4 v = *reinterpret_cast<const float4*>(Xf + (size_t)grow * 128 + u * 4);
            unsigned short h0 = f2bf(v.x), h1 = f2bf(v.y), h2 = f2bf(v.z), h3 = f2bf(v.w);
            unsigned short l0 = f2bf(v.x - bf2f(h0)), l1 = f2bf(v.y - bf2f(h1));
            unsigned short l2 = f2bf(v.z - bf2f(h2)), l3 = f2bf(v.w - bf2f(h3));
            unsigned int* hp = reinterpret_cast<unsigned int*>(&AH[rr * 136 + u * 4]);
            hp[0] = (unsigned int)h0 | ((unsigned int)h1 << 16);
            hp[1] = (unsigned int)h2 | ((unsigned int)h3 << 16);
            unsigned int* lp = reinterpret_cast<unsigned int*>(&AL[rr * 136 + u * 4]);
            lp[0] = (unsigned int)l0 | ((unsigned int)l1 << 16);
            lp[1] = (unsigned int)l2 | ((unsigned int)l3 << 16);
        }
    } else {
#pragma unroll
        for (int i = 0; i < 16; ++i) {
            int sa = i * 256 + tid;
            int a = sa >> 11;
            int s = sa & 2047;
            int rr = s >> 4;
            int u = s & 15;
            const unsigned short* srcp = (a ? Xlo : Xhi) + (size_t)(row0 + rr) * 128 + u * 8;
            unsigned short* dstp = (a ? AL : AH) + rr * 136 + u * 8;
            *reinterpret_cast<uint4*>(dstp) = *reinterpret_cast<const uint4*>(srcp);
        }
    }
    __syncthreads();

    f32x4 acc[2][8];
#pragma unroll
    for (int rt = 0; rt < 2; ++rt)
#pragma unroll
        for (int ct = 0; ct < 8; ++ct)
            acc[rt][ct] = (f32x4){0.f, 0.f, 0.f, 0.f};

#pragma unroll
    for (int ks = 0; ks < 4; ++ks) {
        bf16x8 bh[8], bl[8];
#pragma unroll
        for (int ct = 0; ct < 8; ++ct) {
            size_t off = (size_t)(col0 + ct * 16 + r) * 128 + ks * 32 + kg * 8;
            bh[ct] = *reinterpret_cast<const bf16x8*>(Wth + off);
            bl[ct] = *reinterpret_cast<const bf16x8*>(Wtl + off);
        }
#pragma unroll
        for (int rt = 0; rt < 2; ++rt) {
            int lrow = wave * 32 + rt * 16 + r;
            bf16x8 ah = *reinterpret_cast<const bf16x8*>(&AH[lrow * 136 + ks * 32 + kg * 8]);
            bf16x8 al8 = *reinterpret_cast<const bf16x8*>(&AL[lrow * 136 + ks * 32 + kg * 8]);
#pragma unroll
            for (int ct = 0; ct < 8; ++ct) {
                acc[rt][ct] = __builtin_amdgcn_mfma_f32_16x16x32_bf16(ah, bh[ct], acc[rt][ct], 0, 0, 0);
                acc[rt][ct] = __builtin_amdgcn_mfma_f32_16x16x32_bf16(al8, bh[ct], acc[rt][ct], 0, 0, 0);
                acc[rt][ct] = __builtin_amdgcn_mfma_f32_16x16x32_bf16(ah, bl[ct], acc[rt][ct], 0, 0, 0);
            }
        }
    }

    // ---- epilogue 1: el/er
    constexpr int CTH = DHEAD / 16;
    constexpr int HB = 8 / CTH;
    float als[8], ars[8];
#pragma unroll
    for (int ct = 0; ct < 8; ++ct) {
        als[ct] = alv[col0 + ct * 16 + r];
        ars[ct] = arv[col0 + ct * 16 + r];
    }
    f32x4 pel[2][HB], per_[2][HB];
#pragma unroll
    for (int rt = 0; rt < 2; ++rt)
#pragma unroll
        for (int hl = 0; hl < HB; ++hl) {
            pel[rt][hl] = (f32x4){0.f, 0.f, 0.f, 0.f};
            per_[rt][hl] = (f32x4){0.f, 0.f, 0.f, 0.f};
        }
#pragma unroll
    for (int rt = 0; rt < 2; ++rt)
#pragma unroll
        for (int ct = 0; ct < 8; ++ct) {
            pel[rt][ct / CTH] += acc[rt][ct] * als[ct];
            per_[rt][ct / CTH] += acc[rt][ct] * ars[ct];
        }
#pragma unroll
    for (int off = 1; off < 16; off <<= 1) {
#pragma unroll
        for (int rt = 0; rt < 2; ++rt)
#pragma unroll
            for (int hl = 0; hl < HB; ++hl)
#pragma unroll
                for (int j = 0; j < 4; ++j) {
                    pel[rt][hl][j] += __shfl_xor(pel[rt][hl][j], off);
                    per_[rt][hl][j] += __shfl_xor(per_[rt][hl][j], off);
                }
    }
#pragma unroll
    for (int hl = 0; hl < HB; ++hl) {
        if (r == hl) {
            int hg = col0 / DHEAD + hl;
#pragma unroll
            for (int rt = 0; rt < 2; ++rt)
#pragma unroll
                for (int j = 0; j < 4; ++j) {
                    int grow = row0 + wave * 32 + rt * 16 + kg * 4 + j;
                    if (grow < M) {
                        el[(size_t)grow * 4 + hg] = pel[rt][hl][j];
                        er[(size_t)grow * 4 + hg] = per_[rt][hl][j];
                    }
                }
        }
    }

    // ---- epilogue 2: fp16 h via LDS repack
    __syncthreads();
#pragma unroll
    for (int rt = 0; rt < 2; ++rt)
#pragma unroll
        for (int ct = 0; ct < 8; ++ct)
#pragma unroll
            for (int j = 0; j < 4; ++j) {
                int lrow = wave * 32 + rt * 16 + kg * 4 + j;
                AH[lrow * 136 + ct * 16 + r] = f2h_bits(acc[rt][ct][j]);
            }
    __syncthreads();
#pragma unroll
    for (int it = 0; it < 8; ++it) {
        int idx = it * 256 + tid;
        int rr = idx >> 4;
        int c8 = idx & 15;
        int grow = row0 + rr;
        if (grow < M)
            *reinterpret_cast<uint4*>(Hh + (size_t)grow * ldH + col0 + c8 * 8) =
                *reinterpret_cast<const uint4*>(&AH[rr * 136 + c8 * 8]);
    }
}

// ---------------------------------------------------------------- softmax weights
__global__ __launch_bounds__(256) void alpha_kernel(
    const float* __restrict__ el, const float* __restrict__ er,
    const int* __restrict__ rowptr, const int* __restrict__ csr_src,
    float* __restrict__ ee, float* __restrict__ denom) {
    int wid = (blockIdx.x * 256 + threadIdx.x) >> 6;
    int lane = threadIdx.x & 63;
    if (wid >= N_NODES) return;
    int row0 = rowptr[wid], row1 = rowptr[wid + 1];
    float4 ern = *reinterpret_cast<const float4*>(er + (size_t)wid * 4);

    float4 mx = make_float4(-INFINITY, -INFINITY, -INFINITY, -INFINITY);
    for (int base = row0; base < row1; base += 64) {
        int i = base + lane;
        if (i < row1) {
            int s = csr_src[i];
            float4 e4 = *reinterpret_cast<const float4*>(el + (size_t)s * 4);
            float4 sc;
            sc.x = e4.x + ern.x; sc.x = sc.x > 0.f ? sc.x : 0.2f * sc.x;
            sc.y = e4.y + ern.y; sc.y = sc.y > 0.f ? sc.y : 0.2f * sc.y;
            sc.z = e4.z + ern.z; sc.z = sc.z > 0.f ? sc.z : 0.2f * sc.z;
            sc.w = e4.w + ern.w; sc.w = sc.w > 0.f ? sc.w : 0.2f * sc.w;
            mx.x = fmaxf(mx.x, sc.x); mx.y = fmaxf(mx.y, sc.y);
            mx.z = fmaxf(mx.z, sc.z); mx.w = fmaxf(mx.w, sc.w);
        }
    }
#pragma unroll
    for (int off = 1; off < 64; off <<= 1) {
        mx.x = fmaxf(mx.x, __shfl_xor(mx.x, off));
        mx.y = fmaxf(mx.y, __shfl_xor(mx.y, off));
        mx.z = fmaxf(mx.z, __shfl_xor(mx.z, off));
        mx.w = fmaxf(mx.w, __shfl_xor(mx.w, off));
    }

    float4 sum = make_float4(0.f, 0.f, 0.f, 0.f);
    for (int base = row0; base < row1; base += 64) {
        int i = base + lane;
        if (i < row1) {
            int s = csr_src[i];
            float4 e4 = *reinterpret_cast<const float4*>(el + (size_t)s * 4);
            float4 sc;
            sc.x = e4.x + ern.x; sc.x = sc.x > 0.f ? sc.x : 0.2f * sc.x;
            sc.y = e4.y + ern.y; sc.y = sc.y > 0.f ? sc.y : 0.2f * sc.y;
            sc.z = e4.z + ern.z; sc.z = sc.z > 0.f ? sc.z : 0.2f * sc.z;
            sc.w = e4.w + ern.w; sc.w = sc.w > 0.f ? sc.w : 0.2f * sc.w;
            float4 e;
            e.x = __expf(sc.x - mx.x); e.y = __expf(sc.y - mx.y);
            e.z = __expf(sc.z - mx.z); e.w = __expf(sc.w - mx.w);
            sum.x += e.x; sum.y += e.y; sum.z += e.z; sum.w += e.w;
            *reinterpret_cast<float4*>(ee + (size_t)i * 4) = e;
        }
    }
#pragma unroll
    for (int off = 1; off < 64; off <<= 1) {
        sum.x += __shfl_xor(sum.x, off);
        sum.y += __shfl_xor(sum.y, off);
        sum.z += __shfl_xor(sum.z, off);
        sum.w += __shfl_xor(sum.w, off);
    }
    if (lane == 0) *reinterpret_cast<float4*>(denom + (size_t)wid * 4) = sum;
}

// ---------------------------------------------------------------- weighted gather (fp16 feats)
template <int F, int MODE>
__global__ __launch_bounds__(256) void gather_kernel(
    const _Float16* __restrict__ hfeat, const float* __restrict__ ee,
    const float* __restrict__ denom, const int* __restrict__ rowptr,
    const int* __restrict__ csr_src, const float* __restrict__ bias,
    float* __restrict__ out, unsigned short* __restrict__ ohi,
    unsigned short* __restrict__ olo) {
    constexpr int V = F / 64;
    constexpr int D = F / 4;
    int wid = (blockIdx.x * 256 + threadIdx.x) >> 6;
    int lane = threadIdx.x & 63;
    if (wid >= N_NODES) return;
    int row0 = rowptr[wid], row1 = rowptr[wid + 1];
    int f0 = lane * V;
    int hh = f0 / D;

    float ac0[V], ac1[V], ac2[V], ac3[V];
#pragma unroll
    for (int v = 0; v < V; ++v) { ac0[v] = 0.f; ac1[v] = 0.f; ac2[v] = 0.f; ac3[v] = 0.f; }

    for (int base = row0; base < row1; base += 64) {
        int i = base + lane;
        int sv = (i < row1) ? csr_src[i] : 0;
        int cnt = min(64, row1 - base);
        const float* eep = ee + (size_t)base * 4 + hh;
        int j = 0;
        for (; j + 4 <= cnt; j += 4) {
            int s0 = __shfl(sv, j), s1 = __shfl(sv, j + 1);
            int s2 = __shfl(sv, j + 2), s3 = __shfl(sv, j + 3);
            float w0 = eep[(size_t)(j + 0) * 4], w1 = eep[(size_t)(j + 1) * 4];
            float w2 = eep[(size_t)(j + 2) * 4], w3 = eep[(size_t)(j + 3) * 4];
            if (V == 4) {
                half4_t a = *reinterpret_cast<const half4_t*>(hfeat + (size_t)s0 * F + f0);
                half4_t b = *reinterpret_cast<const half4_t*>(hfeat + (size_t)s1 * F + f0);
                half4_t c = *reinterpret_cast<const half4_t*>(hfeat + (size_t)s2 * F + f0);
                half4_t d = *reinterpret_cast<const half4_t*>(hfeat + (size_t)s3 * F + f0);
#pragma unroll
                for (int v = 0; v < V; ++v) {
                    ac0[v] = fmaf(w0, (float)a[v], ac0[v]);
                    ac1[v] = fmaf(w1, (float)b[v], ac1[v]);
                    ac2[v] = fmaf(w2, (float)c[v], ac2[v]);
                    ac3[v] = fmaf(w3, (float)d[v], ac3[v]);
                }
            } else {
                half2_t a = *reinterpret_cast<const half2_t*>(hfeat + (size_t)s0 * F + f0);
                half2_t b = *reinterpret_cast<const half2_t*>(hfeat + (size_t)s1 * F + f0);
                half2_t c = *reinterpret_cast<const half2_t*>(hfeat + (size_t)s2 * F + f0);
                half2_t d = *reinterpret_cast<const half2_t*>(hfeat + (size_t)s3 * F + f0);
#pragma unroll
                for (int v = 0; v < V; ++v) {
                    ac0[v] = fmaf(w0, (float)a[v], ac0[v]);
                    ac1[v] = fmaf(w1, (float)b[v], ac1[v]);
                    ac2[v] = fmaf(w2, (float)c[v], ac2[v]);
                    ac3[v] = fmaf(w3, (float)d[v], ac3[v]);
                }
            }
        }
        for (; j < cnt; ++j) {
            int s0 = __shfl(sv, j);
            float w0 = eep[(size_t)j * 4];
            if (V == 4) {
                half4_t a = *reinterpret_cast<const half4_t*>(hfeat + (size_t)s0 * F + f0);
#pragma unroll
                for (int v = 0; v < V; ++v) ac0[v] = fmaf(w0, (float)a[v], ac0[v]);
            } else {
                half2_t a = *reinterpret_cast<const half2_t*>(hfeat + (size_t)s0 * F + f0);
#pragma unroll
                for (int v = 0; v < V; ++v) ac0[v] = fmaf(w0, (float)a[v], ac0[v]);
            }
        }
    }

    float dn = denom[(size_t)wid * 4 + hh];
    float inv = dn > 0.f ? 1.f / dn : 0.f;
    float val[V];
#pragma unroll
    for (int v = 0; v < V; ++v)
        val[v] = ((ac0[v] + ac1[v]) + (ac2[v] + ac3[v])) * inv + bias[f0 + v];

    if (MODE == 0) {
#pragma unroll
        for (int v = 0; v < V; ++v)
            val[v] = val[v] > 0.f ? val[v] : (__expf(val[v]) - 1.f);
        unsigned short h0 = f2bf(val[0]), h1 = f2bf(val[1]);
        unsigned short l0 = f2bf(val[0] - bf2f(h0)), l1 = f2bf(val[1] - bf2f(h1));
        reinterpret_cast<unsigned int*>(ohi)[(size_t)wid * (F / 2) + lane] =
            (unsigned int)h0 | ((unsigned int)h1 << 16);
        reinterpret_cast<unsigned int*>(olo)[(size_t)wid * (F / 2) + lane] =
            (unsigned int)l0 | ((unsigned int)l1 << 16);
    } else {
#pragma unroll
        for (int v = 0; v < V; ++v) {
            val[v] += __shfl_xor(val[v], 16);
            val[v] += __shfl_xor(val[v], 32);
        }
        if (lane < 16) {
            float4 o = make_float4(val[0] * 0.25f, val[1] * 0.25f, val[2] * 0.25f, val[3] * 0.25f);
            *reinterpret_cast<float4*>(out + (size_t)wid * D + lane * 4) = o;
        }
    }
}

// ---------------------------------------------------------------- launch
extern "C" void kernel_launch(void* const* d_in, const int* in_sizes, int n_in,
                              void* d_out, int out_size, void* d_ws, size_t ws_size,
                              hipStream_t stream) {
    const float* nfeat = (const float*)d_in[0];
    const int* src = (const int*)d_in[1];
    const int* dst = (const int*)d_in[2];
    const float* W0 = (const float*)d_in[3];
    const float* al0 = (const float*)d_in[4];
    const float* ar0 = (const float*)d_in[5];
    const float* b0 = (const float*)d_in[6];
    const float* W1 = (const float*)d_in[7];
    const float* al1 = (const float*)d_in[8];
    const float* ar1 = (const float*)d_in[9];
    const float* b1 = (const float*)d_in[10];
    const float* W2 = (const float*)d_in[11];
    const float* al2 = (const float*)d_in[12];
    const float* ar2 = (const float*)d_in[13];
    const float* b2 = (const float*)d_in[14];
    float* out = (float*)d_out;

    char* w = (char*)d_ws;
    unsigned short* XA_hi = (unsigned short*)w; w += (size_t)N_NODES * 128 * 2;  // 25.6MB
    unsigned short* XA_lo = (unsigned short*)w; w += (size_t)N_NODES * 128 * 2;
    unsigned short* XB_hi = (unsigned short*)w; w += (size_t)N_NODES * 128 * 2;
    unsigned short* XB_lo = (unsigned short*)w; w += (size_t)N_NODES * 128 * 2;
    _Float16* Ph01 = (_Float16*)w; w += (size_t)N_NODES * 128 * 2;               // 25.6MB
    float* el = (float*)w;     w += (size_t)N_NODES * 4 * 4;
    float* er = (float*)w;     w += (size_t)N_NODES * 4 * 4;
    float* denom = (float*)w;  w += (size_t)N_NODES * 4 * 4;
    int* rowptr = (int*)w;     w += (size_t)(N_NODES + 4) * 4;
    int* deg = (int*)w;        w += (size_t)N_NODES * 4;
    int* bsum = (int*)w;       w += 256 * 4;
    int* csr_src = (int*)w;    w += (size_t)N_EDGES * 4;
    unsigned short* Wt0h = (unsigned short*)w; w += 16384 * 2;
    unsigned short* Wt0l = (unsigned short*)w; w += 16384 * 2;
    unsigned short* Wt1h = (unsigned short*)w; w += 16384 * 2;
    unsigned short* Wt1l = (unsigned short*)w; w += 16384 * 2;
    unsigned short* Wt2h = (unsigned short*)w; w += 32768 * 2;
    unsigned short* Wt2l = (unsigned short*)w; w += 32768 * 2;

    // Aliases (lifetime-checked):
    float* ee0 = (float*)XA_hi;       // XA untouched until gather1 writes it
    float* ee1 = (float*)XB_hi;       // XB dead after GEMM1 reads it
    _Float16* H2h = (_Float16*)XB_hi; // 51.2MB spans XB_hi+XB_lo (dead at GEMM2)
    float* ee2 = (float*)Ph01;        // Ph01 dead after gather1

    const int nb_scan = (N_NODES + 1023) / 1024;

    // ---- W converts
    convert_w_kernel<<<64, 256, 0, stream>>>(W0, Wt0h, Wt0l, 128);
    convert_w_kernel<<<64, 256, 0, stream>>>(W1, Wt1h, Wt1l, 128);
    convert_w_kernel<<<128, 256, 0, stream>>>(W2, Wt2h, Wt2l, 256);

    // ---- CSR build (bucketed scatter: write window L2-resident per pass)
    hipMemsetAsync(deg, 0, (size_t)N_NODES * 4, stream);
    hist_kernel<<<(N_EDGES + 255) / 256, 256, 0, stream>>>(dst, deg);
    scan_block_kernel<<<nb_scan, 256, 0, stream>>>(deg, rowptr, bsum);
    scan_bsum_kernel<<<1, 128, 0, stream>>>(bsum, nb_scan);
    scan_add_kernel<<<(N_NODES + 256) / 256, 256, 0, stream>>>(rowptr, bsum);
    hipMemsetAsync(deg, 0, (size_t)N_NODES * 4, stream);
    {
        const int eb = (N_EDGES + 255) / 256;
        const int rs = (N_NODES + NPASS - 1) / NPASS;
        for (int p = 0; p < NPASS; ++p)
            scatter_pass_kernel<<<eb, 256, 0, stream>>>(src, dst, rowptr, deg, csr_src,
                                                        p * rs, min((p + 1) * rs, N_NODES));
    }

    const int nw_blocks = (N_NODES + 3) / 4;
    dim3 gg1(782, 1), gg2(782, 2);

    // ---- Layer 0 (GEMM stages fp32 nfeat directly; fuses el/er + fp16 h)
    mfma_gemm_kernel<32, true><<<gg1, 256, 0, stream>>>(nullptr, nullptr, nfeat, Wt0h, Wt0l,
                                                        el, er, Ph01, N_NODES, 128, al0, ar0);
    alpha_kernel<<<nw_blocks, 256, 0, stream>>>(el, er, rowptr, csr_src, ee0, denom);
    gather_kernel<128, 0><<<nw_blocks, 256, 0, stream>>>(Ph01, ee0, denom, rowptr, csr_src, b0,
                                                         nullptr, XB_hi, XB_lo);

    // ---- Layer 1
    mfma_gemm_kernel<32, false><<<gg1, 256, 0, stream>>>(XB_hi, XB_lo, nullptr, Wt1h, Wt1l,
                                                         el, er, Ph01, N_NODES, 128, al1, ar1);
    alpha_kernel<<<nw_blocks, 256, 0, stream>>>(el, er, rowptr, csr_src, ee1, denom);
    gather_kernel<128, 0><<<nw_blocks, 256, 0, stream>>>(Ph01, ee1, denom, rowptr, csr_src, b1,
                                                         nullptr, XA_hi, XA_lo);

    // ---- Layer 2
    mfma_gemm_kernel<64, false><<<gg2, 256, 0, stream>>>(XA_hi, XA_lo, nullptr, Wt2h, Wt2l,
                                                         el, er, H2h, N_NODES, 256, al2, ar2);
    alpha_kernel<<<nw_blocks, 256, 0, stream>>>(el, er, rowptr, csr_src, ee2, denom);
    gather_kernel<256, 1><<<nw_blocks, 256, 0, stream>>>(H2h, ee2, denom, rowptr, csr_src, b2,
                                                         out, nullptr, nullptr);
}

// Round 7
// 673.722 us; speedup vs baseline: 2.6555x; 1.2094x over previous
//
#include <hip/hip_runtime.h>
#include <hip/hip_bf16.h>
#include <cstddef>
#include <cstdint>

#define N_NODES 100000
#define N_EDGES 1600000
#define NPASS 4

typedef __attribute__((ext_vector_type(8))) short bf16x8;
typedef __attribute__((ext_vector_type(4))) float f32x4;
typedef __attribute__((ext_vector_type(2))) _Float16 half2_t;
typedef __attribute__((ext_vector_type(4))) _Float16 half4_t;

__device__ inline unsigned short f2bf(float x) {
    unsigned int u = __float_as_uint(x);
    unsigned int r = (u + 0x7fffu + ((u >> 16) & 1u)) >> 16;
    return (unsigned short)r;
}
__device__ inline float bf2f(unsigned short b) {
    return __uint_as_float((unsigned int)b << 16);
}
__device__ inline unsigned short f2h_bits(float x) {
    _Float16 h = (_Float16)x;
    return __builtin_bit_cast(unsigned short, h);
}

// ---------------------------------------------------------------- CSR build
__global__ void hist_kernel(const int* __restrict__ dst, int* __restrict__ deg) {
    int e = blockIdx.x * 256 + threadIdx.x;
    if (e < N_EDGES) atomicAdd(&deg[dst[e]], 1);
}

__global__ void scan_block_kernel(const int* __restrict__ deg, int* __restrict__ rowptr,
                                  int* __restrict__ bsum) {
    __shared__ int s[256];
    int t = threadIdx.x;
    int base = blockIdx.x * 1024 + t * 4;
    int v[4]; int sum = 0;
#pragma unroll
    for (int j = 0; j < 4; ++j) { v[j] = (base + j < N_NODES) ? deg[base + j] : 0; sum += v[j]; }
    s[t] = sum; __syncthreads();
    for (int off = 1; off < 256; off <<= 1) {
        int x = (t >= off) ? s[t - off] : 0;
        __syncthreads();
        s[t] += x;
        __syncthreads();
    }
    int excl = (t > 0) ? s[t - 1] : 0;
    if (t == 255) bsum[blockIdx.x] = s[255];
    int run = excl;
#pragma unroll
    for (int j = 0; j < 4; ++j) { if (base + j < N_NODES) rowptr[base + j] = run; run += v[j]; }
}

__global__ void scan_bsum_kernel(int* bsum, int nb) {
    __shared__ int s[128];
    int t = threadIdx.x;
    int v = (t < nb) ? bsum[t] : 0;
    s[t] = v; __syncthreads();
    for (int off = 1; off < 128; off <<= 1) {
        int x = (t >= off) ? s[t - off] : 0;
        __syncthreads();
        s[t] += x;
        __syncthreads();
    }
    if (t < nb) bsum[t] = (t > 0) ? s[t - 1] : 0;
}

__global__ void scan_add_kernel(int* __restrict__ rowptr, const int* __restrict__ bsum) {
    int i = blockIdx.x * 256 + threadIdx.x;
    if (i < N_NODES) rowptr[i] += bsum[i >> 10];
    if (i == 0) rowptr[N_NODES] = N_EDGES;
}

// Bucketed scatter: write window (csr slab + fill slice) is L2-resident per pass.
__global__ __launch_bounds__(256) void scatter_pass_kernel(
    const int* __restrict__ src, const int* __restrict__ dst,
    const int* __restrict__ rowptr, int* __restrict__ fill,
    int* __restrict__ csr_src, int lo, int hi) {
    int e = blockIdx.x * 256 + threadIdx.x;
    if (e >= N_EDGES) return;
    int d = dst[e];
    if (d >= lo && d < hi) {
        int pos = rowptr[d] + atomicAdd(&fill[d], 1);
        csr_src[pos] = src[e];
    }
}

// ---------------------------------------------------------------- W converts
__global__ __launch_bounds__(256) void convert_w_kernel(const float* __restrict__ W,
                                                        unsigned short* __restrict__ Wth,
                                                        unsigned short* __restrict__ Wtl,
                                                        int Ncols) {
    int t = blockIdx.x * 256 + threadIdx.x;
    if (t >= 128 * Ncols) return;
    int n = t >> 7, k = t & 127;
    float x = W[(size_t)k * Ncols + n];
    unsigned short h = f2bf(x);
    unsigned short l = f2bf(x - bf2f(h));
    Wth[t] = h;
    Wtl[t] = l;
}

// ---------------------------------------------------------------- MFMA split-bf16 GEMM
// FP32IN: stage raw fp32 X, split to bf16 hi/lo during staging (layer 0).
// Fused epilogue: el/er from fp32 acc (16-lane butterfly) + fp16 h via LDS repack.
template <int DHEAD, bool FP32IN>
__global__ __launch_bounds__(256) void mfma_gemm_kernel(
    const unsigned short* __restrict__ Xhi, const unsigned short* __restrict__ Xlo,
    const float* __restrict__ Xf,
    const unsigned short* __restrict__ Wth, const unsigned short* __restrict__ Wtl,
    float* __restrict__ el, float* __restrict__ er, _Float16* __restrict__ Hh,
    int M, int ldH, const float* __restrict__ alv, const float* __restrict__ arv) {
    __shared__ unsigned short AH[128 * 136];
    __shared__ unsigned short AL[128 * 136];
    const int tid = threadIdx.x;
    const int wave = tid >> 6, lane = tid & 63;
    const int r = lane & 15, kg = lane >> 4;
    const int row0 = blockIdx.x * 128;
    const int col0 = blockIdx.y * 128;

    if constexpr (FP32IN) {
#pragma unroll
        for (int i = 0; i < 16; ++i) {
            int idx = i * 256 + tid;
            int rr = idx >> 5;
            int u = idx & 31;
            int grow = row0 + rr;
            if (grow > M - 1) grow = M - 1;
            float4 v = *reinterpret_cast<const float4*>(Xf + (size_t)grow * 128 + u * 4);
            unsigned short h0 = f2bf(v.x), h1 = f2bf(v.y), h2 = f2bf(v.z), h3 = f2bf(v.w);
            unsigned short l0 = f2bf(v.x - bf2f(h0)), l1 = f2bf(v.y - bf2f(h1));
            unsigned short l2 = f2bf(v.z - bf2f(h2)), l3 = f2bf(v.w - bf2f(h3));
            unsigned int* hp = reinterpret_cast<unsigned int*>(&AH[rr * 136 + u * 4]);
            hp[0] = (unsigned int)h0 | ((unsigned int)h1 << 16);
            hp[1] = (unsigned int)h2 | ((unsigned int)h3 << 16);
            unsigned int* lp = reinterpret_cast<unsigned int*>(&AL[rr * 136 + u * 4]);
            lp[0] = (unsigned int)l0 | ((unsigned int)l1 << 16);
            lp[1] = (unsigned int)l2 | ((unsigned int)l3 << 16);
        }
    } else {
#pragma unroll
        for (int i = 0; i < 16; ++i) {
            int sa = i * 256 + tid;
            int a = sa >> 11;
            int s = sa & 2047;
            int rr = s >> 4;
            int u = s & 15;
            const unsigned short* srcp = (a ? Xlo : Xhi) + (size_t)(row0 + rr) * 128 + u * 8;
            unsigned short* dstp = (a ? AL : AH) + rr * 136 + u * 8;
            *reinterpret_cast<uint4*>(dstp) = *reinterpret_cast<const uint4*>(srcp);
        }
    }
    __syncthreads();

    f32x4 acc[2][8];
#pragma unroll
    for (int rt = 0; rt < 2; ++rt)
#pragma unroll
        for (int ct = 0; ct < 8; ++ct)
            acc[rt][ct] = (f32x4){0.f, 0.f, 0.f, 0.f};

#pragma unroll
    for (int ks = 0; ks < 4; ++ks) {
        bf16x8 bh[8], bl[8];
#pragma unroll
        for (int ct = 0; ct < 8; ++ct) {
            size_t off = (size_t)(col0 + ct * 16 + r) * 128 + ks * 32 + kg * 8;
            bh[ct] = *reinterpret_cast<const bf16x8*>(Wth + off);
            bl[ct] = *reinterpret_cast<const bf16x8*>(Wtl + off);
        }
#pragma unroll
        for (int rt = 0; rt < 2; ++rt) {
            int lrow = wave * 32 + rt * 16 + r;
            bf16x8 ah = *reinterpret_cast<const bf16x8*>(&AH[lrow * 136 + ks * 32 + kg * 8]);
            bf16x8 al8 = *reinterpret_cast<const bf16x8*>(&AL[lrow * 136 + ks * 32 + kg * 8]);
#pragma unroll
            for (int ct = 0; ct < 8; ++ct) {
                acc[rt][ct] = __builtin_amdgcn_mfma_f32_16x16x32_bf16(ah, bh[ct], acc[rt][ct], 0, 0, 0);
                acc[rt][ct] = __builtin_amdgcn_mfma_f32_16x16x32_bf16(al8, bh[ct], acc[rt][ct], 0, 0, 0);
                acc[rt][ct] = __builtin_amdgcn_mfma_f32_16x16x32_bf16(ah, bl[ct], acc[rt][ct], 0, 0, 0);
            }
        }
    }

    // ---- epilogue 1: el/er
    constexpr int CTH = DHEAD / 16;
    constexpr int HB = 8 / CTH;
    float als[8], ars[8];
#pragma unroll
    for (int ct = 0; ct < 8; ++ct) {
        als[ct] = alv[col0 + ct * 16 + r];
        ars[ct] = arv[col0 + ct * 16 + r];
    }
    f32x4 pel[2][HB], per_[2][HB];
#pragma unroll
    for (int rt = 0; rt < 2; ++rt)
#pragma unroll
        for (int hl = 0; hl < HB; ++hl) {
            pel[rt][hl] = (f32x4){0.f, 0.f, 0.f, 0.f};
            per_[rt][hl] = (f32x4){0.f, 0.f, 0.f, 0.f};
        }
#pragma unroll
    for (int rt = 0; rt < 2; ++rt)
#pragma unroll
        for (int ct = 0; ct < 8; ++ct) {
            pel[rt][ct / CTH] += acc[rt][ct] * als[ct];
            per_[rt][ct / CTH] += acc[rt][ct] * ars[ct];
        }
#pragma unroll
    for (int off = 1; off < 16; off <<= 1) {
#pragma unroll
        for (int rt = 0; rt < 2; ++rt)
#pragma unroll
            for (int hl = 0; hl < HB; ++hl)
#pragma unroll
                for (int j = 0; j < 4; ++j) {
                    pel[rt][hl][j] += __shfl_xor(pel[rt][hl][j], off);
                    per_[rt][hl][j] += __shfl_xor(per_[rt][hl][j], off);
                }
    }
#pragma unroll
    for (int hl = 0; hl < HB; ++hl) {
        if (r == hl) {
            int hg = col0 / DHEAD + hl;
#pragma unroll
            for (int rt = 0; rt < 2; ++rt)
#pragma unroll
                for (int j = 0; j < 4; ++j) {
                    int grow = row0 + wave * 32 + rt * 16 + kg * 4 + j;
                    if (grow < M) {
                        el[(size_t)grow * 4 + hg] = pel[rt][hl][j];
                        er[(size_t)grow * 4 + hg] = per_[rt][hl][j];
                    }
                }
        }
    }

    // ---- epilogue 2: fp16 h via LDS repack
    __syncthreads();
#pragma unroll
    for (int rt = 0; rt < 2; ++rt)
#pragma unroll
        for (int ct = 0; ct < 8; ++ct)
#pragma unroll
            for (int j = 0; j < 4; ++j) {
                int lrow = wave * 32 + rt * 16 + kg * 4 + j;
                AH[lrow * 136 + ct * 16 + r] = f2h_bits(acc[rt][ct][j]);
            }
    __syncthreads();
#pragma unroll
    for (int it = 0; it < 8; ++it) {
        int idx = it * 256 + tid;
        int rr = idx >> 4;
        int c8 = idx & 15;
        int grow = row0 + rr;
        if (grow < M)
            *reinterpret_cast<uint4*>(Hh + (size_t)grow * ldH + col0 + c8 * 8) =
                *reinterpret_cast<const uint4*>(&AH[rr * 136 + c8 * 8]);
    }
}

// ---------------------------------------------------------------- fused softmax+gather
// Wave per node. Per 64-edge chunk: lane i computes exp(leaky(el[s_i]+er[n]))
// for all 4 heads of ITS edge (float4), parks in per-wave LDS; the j-loop
// reads w = ws[j*4+hh] (broadcast, conflict-free) and accumulates both the
// weighted feature sum and the softmax denominator; normalize in epilogue.
// Max-subtraction dropped: scores bounded (|s| << 88), softmax shift-invariant.
// MODE 0: elu -> bf16 hi/lo [N,F].  MODE 1: head-mean -> out[N,F/4] fp32.
template <int F, int MODE>
__global__ __launch_bounds__(256) void sgather_kernel(
    const _Float16* __restrict__ hfeat, const float* __restrict__ el,
    const float* __restrict__ er, const int* __restrict__ rowptr,
    const int* __restrict__ csr_src, const float* __restrict__ bias,
    float* __restrict__ out, unsigned short* __restrict__ ohi,
    unsigned short* __restrict__ olo) {
    constexpr int V = F / 64;
    constexpr int D = F / 4;
    __shared__ float wsh[4][256];
    int wv = threadIdx.x >> 6;
    int wid = (blockIdx.x * 256 + threadIdx.x) >> 6;
    int lane = threadIdx.x & 63;
    if (wid >= N_NODES) return;
    int row0 = rowptr[wid], row1 = rowptr[wid + 1];
    int f0 = lane * V;
    int hh = lane >> 4;               // == f0 / D for both F=128,256
    float4 ern = *reinterpret_cast<const float4*>(er + (size_t)wid * 4);

    float ac0[V], ac1[V], ac2[V], ac3[V];
#pragma unroll
    for (int v = 0; v < V; ++v) { ac0[v] = 0.f; ac1[v] = 0.f; ac2[v] = 0.f; ac3[v] = 0.f; }
    float den = 0.f;

    for (int base = row0; base < row1; base += 64) {
        int i = base + lane;
        int sv = (i < row1) ? csr_src[i] : 0;
        // scores for this lane's edge, all 4 heads
        float4 e4 = *reinterpret_cast<const float4*>(el + (size_t)sv * 4);
        float4 es;
        es.x = e4.x + ern.x; es.x = es.x > 0.f ? es.x : 0.2f * es.x; es.x = __expf(es.x);
        es.y = e4.y + ern.y; es.y = es.y > 0.f ? es.y : 0.2f * es.y; es.y = __expf(es.y);
        es.z = e4.z + ern.z; es.z = es.z > 0.f ? es.z : 0.2f * es.z; es.z = __expf(es.z);
        es.w = e4.w + ern.w; es.w = es.w > 0.f ? es.w : 0.2f * es.w; es.w = __expf(es.w);
        *reinterpret_cast<float4*>(&wsh[wv][lane * 4]) = es;   // same-wave DS: ordered

        int cnt = min(64, row1 - base);
        const float* wp = &wsh[wv][hh];
        int j = 0;
        for (; j + 4 <= cnt; j += 4) {
            int s0 = __shfl(sv, j), s1 = __shfl(sv, j + 1);
            int s2 = __shfl(sv, j + 2), s3 = __shfl(sv, j + 3);
            float w0 = wp[(j + 0) * 4], w1 = wp[(j + 1) * 4];
            float w2 = wp[(j + 2) * 4], w3 = wp[(j + 3) * 4];
            den += (w0 + w1) + (w2 + w3);
            if (V == 4) {
                half4_t a = *reinterpret_cast<const half4_t*>(hfeat + (size_t)s0 * F + f0);
                half4_t b = *reinterpret_cast<const half4_t*>(hfeat + (size_t)s1 * F + f0);
                half4_t c = *reinterpret_cast<const half4_t*>(hfeat + (size_t)s2 * F + f0);
                half4_t d = *reinterpret_cast<const half4_t*>(hfeat + (size_t)s3 * F + f0);
#pragma unroll
                for (int v = 0; v < V; ++v) {
                    ac0[v] = fmaf(w0, (float)a[v], ac0[v]);
                    ac1[v] = fmaf(w1, (float)b[v], ac1[v]);
                    ac2[v] = fmaf(w2, (float)c[v], ac2[v]);
                    ac3[v] = fmaf(w3, (float)d[v], ac3[v]);
                }
            } else {
                half2_t a = *reinterpret_cast<const half2_t*>(hfeat + (size_t)s0 * F + f0);
                half2_t b = *reinterpret_cast<const half2_t*>(hfeat + (size_t)s1 * F + f0);
                half2_t c = *reinterpret_cast<const half2_t*>(hfeat + (size_t)s2 * F + f0);
                half2_t d = *reinterpret_cast<const half2_t*>(hfeat + (size_t)s3 * F + f0);
#pragma unroll
                for (int v = 0; v < V; ++v) {
                    ac0[v] = fmaf(w0, (float)a[v], ac0[v]);
                    ac1[v] = fmaf(w1, (float)b[v], ac1[v]);
                    ac2[v] = fmaf(w2, (float)c[v], ac2[v]);
                    ac3[v] = fmaf(w3, (float)d[v], ac3[v]);
                }
            }
        }
        for (; j < cnt; ++j) {
            int s0 = __shfl(sv, j);
            float w0 = wp[(size_t)j * 4];
            den += w0;
            if (V == 4) {
                half4_t a = *reinterpret_cast<const half4_t*>(hfeat + (size_t)s0 * F + f0);
#pragma unroll
                for (int v = 0; v < V; ++v) ac0[v] = fmaf(w0, (float)a[v], ac0[v]);
            } else {
                half2_t a = *reinterpret_cast<const half2_t*>(hfeat + (size_t)s0 * F + f0);
#pragma unroll
                for (int v = 0; v < V; ++v) ac0[v] = fmaf(w0, (float)a[v], ac0[v]);
            }
        }
    }

    float inv = den > 0.f ? 1.f / den : 0.f;
    float val[V];
#pragma unroll
    for (int v = 0; v < V; ++v)
        val[v] = ((ac0[v] + ac1[v]) + (ac2[v] + ac3[v])) * inv + bias[f0 + v];

    if (MODE == 0) {
#pragma unroll
        for (int v = 0; v < V; ++v)
            val[v] = val[v] > 0.f ? val[v] : (__expf(val[v]) - 1.f);
        unsigned short h0 = f2bf(val[0]), h1 = f2bf(val[1]);
        unsigned short l0 = f2bf(val[0] - bf2f(h0)), l1 = f2bf(val[1] - bf2f(h1));
        reinterpret_cast<unsigned int*>(ohi)[(size_t)wid * (F / 2) + lane] =
            (unsigned int)h0 | ((unsigned int)h1 << 16);
        reinterpret_cast<unsigned int*>(olo)[(size_t)wid * (F / 2) + lane] =
            (unsigned int)l0 | ((unsigned int)l1 << 16);
    } else {
#pragma unroll
        for (int v = 0; v < V; ++v) {
            val[v] += __shfl_xor(val[v], 16);
            val[v] += __shfl_xor(val[v], 32);
        }
        if (lane < 16) {
            float4 o = make_float4(val[0] * 0.25f, val[1] * 0.25f, val[2] * 0.25f, val[3] * 0.25f);
            *reinterpret_cast<float4*>(out + (size_t)wid * D + lane * 4) = o;
        }
    }
}

// ---------------------------------------------------------------- launch
extern "C" void kernel_launch(void* const* d_in, const int* in_sizes, int n_in,
                              void* d_out, int out_size, void* d_ws, size_t ws_size,
                              hipStream_t stream) {
    const float* nfeat = (const float*)d_in[0];
    const int* src = (const int*)d_in[1];
    const int* dst = (const int*)d_in[2];
    const float* W0 = (const float*)d_in[3];
    const float* al0 = (const float*)d_in[4];
    const float* ar0 = (const float*)d_in[5];
    const float* b0 = (const float*)d_in[6];
    const float* W1 = (const float*)d_in[7];
    const float* al1 = (const float*)d_in[8];
    const float* ar1 = (const float*)d_in[9];
    const float* b1 = (const float*)d_in[10];
    const float* W2 = (const float*)d_in[11];
    const float* al2 = (const float*)d_in[12];
    const float* ar2 = (const float*)d_in[13];
    const float* b2 = (const float*)d_in[14];
    float* out = (float*)d_out;

    char* w = (char*)d_ws;
    unsigned short* XA_hi = (unsigned short*)w; w += (size_t)N_NODES * 128 * 2;  // 25.6MB
    unsigned short* XA_lo = (unsigned short*)w; w += (size_t)N_NODES * 128 * 2;
    unsigned short* XB_hi = (unsigned short*)w; w += (size_t)N_NODES * 128 * 2;
    unsigned short* XB_lo = (unsigned short*)w; w += (size_t)N_NODES * 128 * 2;
    _Float16* Ph01 = (_Float16*)w; w += (size_t)N_NODES * 128 * 2;               // 25.6MB
    float* el = (float*)w;     w += (size_t)N_NODES * 4 * 4;
    float* er = (float*)w;     w += (size_t)N_NODES * 4 * 4;
    int* rowptr = (int*)w;     w += (size_t)(N_NODES + 4) * 4;
    int* deg = (int*)w;        w += (size_t)N_NODES * 4;
    int* bsum = (int*)w;       w += 256 * 4;
    int* csr_src = (int*)w;    w += (size_t)N_EDGES * 4;
    unsigned short* Wt0h = (unsigned short*)w; w += 16384 * 2;
    unsigned short* Wt0l = (unsigned short*)w; w += 16384 * 2;
    unsigned short* Wt1h = (unsigned short*)w; w += 16384 * 2;
    unsigned short* Wt1l = (unsigned short*)w; w += 16384 * 2;
    unsigned short* Wt2h = (unsigned short*)w; w += 32768 * 2;
    unsigned short* Wt2l = (unsigned short*)w; w += 32768 * 2;

    // Aliases (lifetime-checked):
    _Float16* H2h = (_Float16*)XB_hi; // 51.2MB spans XB_hi+XB_lo (dead at GEMM2)

    const int nb_scan = (N_NODES + 1023) / 1024;

    // ---- W converts
    convert_w_kernel<<<64, 256, 0, stream>>>(W0, Wt0h, Wt0l, 128);
    convert_w_kernel<<<64, 256, 0, stream>>>(W1, Wt1h, Wt1l, 128);
    convert_w_kernel<<<128, 256, 0, stream>>>(W2, Wt2h, Wt2l, 256);

    // ---- CSR build (bucketed scatter: write window per-XCD-L2-resident)
    hipMemsetAsync(deg, 0, (size_t)N_NODES * 4, stream);
    hist_kernel<<<(N_EDGES + 255) / 256, 256, 0, stream>>>(dst, deg);
    scan_block_kernel<<<nb_scan, 256, 0, stream>>>(deg, rowptr, bsum);
    scan_bsum_kernel<<<1, 128, 0, stream>>>(bsum, nb_scan);
    scan_add_kernel<<<(N_NODES + 256) / 256, 256, 0, stream>>>(rowptr, bsum);
    hipMemsetAsync(deg, 0, (size_t)N_NODES * 4, stream);
    {
        const int eb = (N_EDGES + 255) / 256;
        const int rs = (N_NODES + NPASS - 1) / NPASS;
        for (int p = 0; p < NPASS; ++p)
            scatter_pass_kernel<<<eb, 256, 0, stream>>>(src, dst, rowptr, deg, csr_src,
                                                        p * rs, min((p + 1) * rs, N_NODES));
    }

    const int nw_blocks = (N_NODES + 3) / 4;
    dim3 gg1(782, 1), gg2(782, 2);

    // ---- Layer 0 (GEMM stages fp32 nfeat; fuses el/er + fp16 h)
    mfma_gemm_kernel<32, true><<<gg1, 256, 0, stream>>>(nullptr, nullptr, nfeat, Wt0h, Wt0l,
                                                        el, er, Ph01, N_NODES, 128, al0, ar0);
    sgather_kernel<128, 0><<<nw_blocks, 256, 0, stream>>>(Ph01, el, er, rowptr, csr_src, b0,
                                                          nullptr, XB_hi, XB_lo);

    // ---- Layer 1
    mfma_gemm_kernel<32, false><<<gg1, 256, 0, stream>>>(XB_hi, XB_lo, nullptr, Wt1h, Wt1l,
                                                         el, er, Ph01, N_NODES, 128, al1, ar1);
    sgather_kernel<128, 0><<<nw_blocks, 256, 0, stream>>>(Ph01, el, er, rowptr, csr_src, b1,
                                                          nullptr, XA_hi, XA_lo);

    // ---- Layer 2
    mfma_gemm_kernel<64, false><<<gg2, 256, 0, stream>>>(XA_hi, XA_lo, nullptr, Wt2h, Wt2l,
                                                         el, er, H2h, N_NODES, 256, al2, ar2);
    sgather_kernel<256, 1><<<nw_blocks, 256, 0, stream>>>(H2h, el, er, rowptr, csr_src, b2,
                                                          out, nullptr, nullptr);
}

// Round 10
// 665.888 us; speedup vs baseline: 2.6868x; 1.0118x over previous
//
#include <hip/hip_runtime.h>
#include <hip/hip_bf16.h>
#include <cstddef>
#include <cstdint>

#define N_NODES 100000
#define N_EDGES 1600000
#define NPASS 4

typedef __attribute__((ext_vector_type(8))) short bf16x8;
typedef __attribute__((ext_vector_type(4))) float f32x4;
typedef __attribute__((ext_vector_type(2))) _Float16 half2_t;
typedef __attribute__((ext_vector_type(4))) _Float16 half4_t;
typedef __attribute__((ext_vector_type(8))) _Float16 half8_t;

__device__ inline unsigned short f2bf(float x) {
    unsigned int u = __float_as_uint(x);
    unsigned int r = (u + 0x7fffu + ((u >> 16) & 1u)) >> 16;
    return (unsigned short)r;
}
__device__ inline float bf2f(unsigned short b) {
    return __uint_as_float((unsigned int)b << 16);
}
__device__ inline unsigned short f2h_bits(float x) {
    _Float16 h = (_Float16)x;
    return __builtin_bit_cast(unsigned short, h);
}

// ---------------------------------------------------------------- CSR build
__global__ void hist_kernel(const int* __restrict__ dst, int* __restrict__ deg) {
    int e = blockIdx.x * 256 + threadIdx.x;
    if (e < N_EDGES) atomicAdd(&deg[dst[e]], 1);
}

__global__ void scan_block_kernel(const int* __restrict__ deg, int* __restrict__ rowptr,
                                  int* __restrict__ bsum) {
    __shared__ int s[256];
    int t = threadIdx.x;
    int base = blockIdx.x * 1024 + t * 4;
    int v[4]; int sum = 0;
#pragma unroll
    for (int j = 0; j < 4; ++j) { v[j] = (base + j < N_NODES) ? deg[base + j] : 0; sum += v[j]; }
    s[t] = sum; __syncthreads();
    for (int off = 1; off < 256; off <<= 1) {
        int x = (t >= off) ? s[t - off] : 0;
        __syncthreads();
        s[t] += x;
        __syncthreads();
    }
    int excl = (t > 0) ? s[t - 1] : 0;
    if (t == 255) bsum[blockIdx.x] = s[255];
    int run = excl;
#pragma unroll
    for (int j = 0; j < 4; ++j) { if (base + j < N_NODES) rowptr[base + j] = run; run += v[j]; }
}

__global__ void scan_bsum_kernel(int* bsum, int nb) {
    __shared__ int s[128];
    int t = threadIdx.x;
    int v = (t < nb) ? bsum[t] : 0;
    s[t] = v; __syncthreads();
    for (int off = 1; off < 128; off <<= 1) {
        int x = (t >= off) ? s[t - off] : 0;
        __syncthreads();
        s[t] += x;
        __syncthreads();
    }
    if (t < nb) bsum[t] = (t > 0) ? s[t - 1] : 0;
}

__global__ void scan_add_kernel(int* __restrict__ rowptr, const int* __restrict__ bsum) {
    int i = blockIdx.x * 256 + threadIdx.x;
    if (i < N_NODES) rowptr[i] += bsum[i >> 10];
    if (i == 0) rowptr[N_NODES] = N_EDGES;
}

// Bucketed scatter: write window (csr slab + fill slice) is L2-resident per pass.
__global__ __launch_bounds__(256) void scatter_pass_kernel(
    const int* __restrict__ src, const int* __restrict__ dst,
    const int* __restrict__ rowptr, int* __restrict__ fill,
    int* __restrict__ csr_src, int lo, int hi) {
    int e = blockIdx.x * 256 + threadIdx.x;
    if (e >= N_EDGES) return;
    int d = dst[e];
    if (d >= lo && d < hi) {
        int pos = rowptr[d] + atomicAdd(&fill[d], 1);
        csr_src[pos] = src[e];
    }
}

// ---------------------------------------------------------------- W converts
__global__ __launch_bounds__(256) void convert_w_kernel(const float* __restrict__ W,
                                                        unsigned short* __restrict__ Wth,
                                                        unsigned short* __restrict__ Wtl,
                                                        int Ncols) {
    int t = blockIdx.x * 256 + threadIdx.x;
    if (t >= 128 * Ncols) return;
    int n = t >> 7, k = t & 127;
    float x = W[(size_t)k * Ncols + n];
    unsigned short h = f2bf(x);
    unsigned short l = f2bf(x - bf2f(h));
    Wth[t] = h;
    Wtl[t] = l;
}

// ---------------------------------------------------------------- MFMA split-bf16 GEMM
// FP32IN: stage raw fp32 X, split to bf16 hi/lo during staging (layer 0).
// Fused epilogue: el/er from fp32 acc (16-lane butterfly) + fp16 h via LDS repack.
template <int DHEAD, bool FP32IN>
__global__ __launch_bounds__(256) void mfma_gemm_kernel(
    const unsigned short* __restrict__ Xhi, const unsigned short* __restrict__ Xlo,
    const float* __restrict__ Xf,
    const unsigned short* __restrict__ Wth, const unsigned short* __restrict__ Wtl,
    float* __restrict__ el, float* __restrict__ er, _Float16* __restrict__ Hh,
    int M, int ldH, const float* __restrict__ alv, const float* __restrict__ arv) {
    __shared__ unsigned short AH[128 * 136];
    __shared__ unsigned short AL[128 * 136];
    const int tid = threadIdx.x;
    const int wave = tid >> 6, lane = tid & 63;
    const int r = lane & 15, kg = lane >> 4;
    const int row0 = blockIdx.x * 128;
    const int col0 = blockIdx.y * 128;

    if constexpr (FP32IN) {
#pragma unroll
        for (int i = 0; i < 16; ++i) {
            int idx = i * 256 + tid;
            int rr = idx >> 5;
            int u = idx & 31;
            int grow = row0 + rr;
            if (grow > M - 1) grow = M - 1;
            float4 v = *reinterpret_cast<const float4*>(Xf + (size_t)grow * 128 + u * 4);
            unsigned short h0 = f2bf(v.x), h1 = f2bf(v.y), h2 = f2bf(v.z), h3 = f2bf(v.w);
            unsigned short l0 = f2bf(v.x - bf2f(h0)), l1 = f2bf(v.y - bf2f(h1));
            unsigned short l2 = f2bf(v.z - bf2f(h2)), l3 = f2bf(v.w - bf2f(h3));
            unsigned int* hp = reinterpret_cast<unsigned int*>(&AH[rr * 136 + u * 4]);
            hp[0] = (unsigned int)h0 | ((unsigned int)h1 << 16);
            hp[1] = (unsigned int)h2 | ((unsigned int)h3 << 16);
            unsigned int* lp = reinterpret_cast<unsigned int*>(&AL[rr * 136 + u * 4]);
            lp[0] = (unsigned int)l0 | ((unsigned int)l1 << 16);
            lp[1] = (unsigned int)l2 | ((unsigned int)l3 << 16);
        }
    } else {
#pragma unroll
        for (int i = 0; i < 16; ++i) {
            int sa = i * 256 + tid;
            int a = sa >> 11;
            int s = sa & 2047;
            int rr = s >> 4;
            int u = s & 15;
            const unsigned short* srcp = (a ? Xlo : Xhi) + (size_t)(row0 + rr) * 128 + u * 8;
            unsigned short* dstp = (a ? AL : AH) + rr * 136 + u * 8;
            *reinterpret_cast<uint4*>(dstp) = *reinterpret_cast<const uint4*>(srcp);
        }
    }
    __syncthreads();

    f32x4 acc[2][8];
#pragma unroll
    for (int rt = 0; rt < 2; ++rt)
#pragma unroll
        for (int ct = 0; ct < 8; ++ct)
            acc[rt][ct] = (f32x4){0.f, 0.f, 0.f, 0.f};

#pragma unroll
    for (int ks = 0; ks < 4; ++ks) {
        bf16x8 bh[8], bl[8];
#pragma unroll
        for (int ct = 0; ct < 8; ++ct) {
            size_t off = (size_t)(col0 + ct * 16 + r) * 128 + ks * 32 + kg * 8;
            bh[ct] = *reinterpret_cast<const bf16x8*>(Wth + off);
            bl[ct] = *reinterpret_cast<const bf16x8*>(Wtl + off);
        }
#pragma unroll
        for (int rt = 0; rt < 2; ++rt) {
            int lrow = wave * 32 + rt * 16 + r;
            bf16x8 ah = *reinterpret_cast<const bf16x8*>(&AH[lrow * 136 + ks * 32 + kg * 8]);
            bf16x8 al8 = *reinterpret_cast<const bf16x8*>(&AL[lrow * 136 + ks * 32 + kg * 8]);
#pragma unroll
            for (int ct = 0; ct < 8; ++ct) {
                acc[rt][ct] = __builtin_amdgcn_mfma_f32_16x16x32_bf16(ah, bh[ct], acc[rt][ct], 0, 0, 0);
                acc[rt][ct] = __builtin_amdgcn_mfma_f32_16x16x32_bf16(al8, bh[ct], acc[rt][ct], 0, 0, 0);
                acc[rt][ct] = __builtin_amdgcn_mfma_f32_16x16x32_bf16(ah, bl[ct], acc[rt][ct], 0, 0, 0);
            }
        }
    }

    // ---- epilogue 1: el/er
    constexpr int CTH = DHEAD / 16;
    constexpr int HB = 8 / CTH;
    float als[8], ars[8];
#pragma unroll
    for (int ct = 0; ct < 8; ++ct) {
        als[ct] = alv[col0 + ct * 16 + r];
        ars[ct] = arv[col0 + ct * 16 + r];
    }
    f32x4 pel[2][HB], per_[2][HB];
#pragma unroll
    for (int rt = 0; rt < 2; ++rt)
#pragma unroll
        for (int hl = 0; hl < HB; ++hl) {
            pel[rt][hl] = (f32x4){0.f, 0.f, 0.f, 0.f};
            per_[rt][hl] = (f32x4){0.f, 0.f, 0.f, 0.f};
        }
#pragma unroll
    for (int rt = 0; rt < 2; ++rt)
#pragma unroll
        for (int ct = 0; ct < 8; ++ct) {
            pel[rt][ct / CTH] += acc[rt][ct] * als[ct];
            per_[rt][ct / CTH] += acc[rt][ct] * ars[ct];
        }
#pragma unroll
    for (int off = 1; off < 16; off <<= 1) {
#pragma unroll
        for (int rt = 0; rt < 2; ++rt)
#pragma unroll
            for (int hl = 0; hl < HB; ++hl)
#pragma unroll
                for (int j = 0; j < 4; ++j) {
                    pel[rt][hl][j] += __shfl_xor(pel[rt][hl][j], off);
                    per_[rt][hl][j] += __shfl_xor(per_[rt][hl][j], off);
                }
    }
#pragma unroll
    for (int hl = 0; hl < HB; ++hl) {
        if (r == hl) {
            int hg = col0 / DHEAD + hl;
#pragma unroll
            for (int rt = 0; rt < 2; ++rt)
#pragma unroll
                for (int j = 0; j < 4; ++j) {
                    int grow = row0 + wave * 32 + rt * 16 + kg * 4 + j;
                    if (grow < M) {
                        el[(size_t)grow * 4 + hg] = pel[rt][hl][j];
                        er[(size_t)grow * 4 + hg] = per_[rt][hl][j];
                    }
                }
        }
    }

    // ---- epilogue 2: fp16 h via LDS repack
    __syncthreads();
#pragma unroll
    for (int rt = 0; rt < 2; ++rt)
#pragma unroll
        for (int ct = 0; ct < 8; ++ct)
#pragma unroll
            for (int j = 0; j < 4; ++j) {
                int lrow = wave * 32 + rt * 16 + kg * 4 + j;
                AH[lrow * 136 + ct * 16 + r] = f2h_bits(acc[rt][ct][j]);
            }
    __syncthreads();
#pragma unroll
    for (int it = 0; it < 8; ++it) {
        int idx = it * 256 + tid;
        int rr = idx >> 4;
        int c8 = idx & 15;
        int grow = row0 + rr;
        if (grow < M)
            *reinterpret_cast<uint4*>(Hh + (size_t)grow * ldH + col0 + c8 * 8) =
                *reinterpret_cast<const uint4*>(&AH[rr * 136 + c8 * 8]);
    }
}

// ---------------------------------------------------------------- fused softmax+gather
// TWO NODES PER WAVE (half-wave = one node, 32 lanes). Lane hl owns V=F/32
// consecutive feats (8B half4 for F=128, 16B half8 for F=256); head hh=hl>>3.
// BIT-IDENTICAL summation to the round-7 kernel: chunk=32 is a multiple of 4,
// so chain assignment (e mod 4 -> ac0..ac3, tail singles -> ac0), the den
// group-of-4 tree, ((ac0+ac1)+(ac2+ac3))*inv+bias, and the head-mean
// ((h0+h1)+(h2+h3)) tree are all preserved exactly per node.
// Compiler memory fences around the wsh write prevent LDS write/read
// reordering (suspected cause of the r8/r9 failures).
// MODE 0: elu -> bf16 hi/lo [N,F].  MODE 1: head-mean -> out[N,F/4] fp32.
template <int F, int MODE>
__global__ __launch_bounds__(256) void sgather2_kernel(
    const _Float16* __restrict__ hfeat, const float* __restrict__ el,
    const float* __restrict__ er, const int* __restrict__ rowptr,
    const int* __restrict__ csr_src, const float* __restrict__ bias,
    float* __restrict__ out, unsigned short* __restrict__ ohi,
    unsigned short* __restrict__ olo) {
    constexpr int V = F / 32;             // 4 (F=128) or 8 (F=256)
    constexpr int D = F / 4;
    __shared__ float wsh[4][2][128];
    int wv = threadIdx.x >> 6;
    int lane = threadIdx.x & 63;
    int hw = lane >> 5;                   // which half-wave (node select)
    int hl = lane & 31;                   // lane within half-wave
    int wid = blockIdx.x * 8 + (threadIdx.x >> 5);
    if (wid >= N_NODES) return;
    int row0 = rowptr[wid], row1 = rowptr[wid + 1];
    int f0 = hl * V;
    int hh = hl >> 3;                     // = f0 / D for both F=128,256
    float4 ern = *reinterpret_cast<const float4*>(er + (size_t)wid * 4);

    float ac0[V], ac1[V], ac2[V], ac3[V];
#pragma unroll
    for (int v = 0; v < V; ++v) { ac0[v] = 0.f; ac1[v] = 0.f; ac2[v] = 0.f; ac3[v] = 0.f; }
    float den = 0.f;

    for (int base = row0; base < row1; base += 32) {
        int i = base + hl;
        int sv = (i < row1) ? csr_src[i] : 0;
        float4 e4 = *reinterpret_cast<const float4*>(el + (size_t)sv * 4);
        float4 es;
        es.x = e4.x + ern.x; es.x = es.x > 0.f ? es.x : 0.2f * es.x; es.x = __expf(es.x);
        es.y = e4.y + ern.y; es.y = es.y > 0.f ? es.y : 0.2f * es.y; es.y = __expf(es.y);
        es.z = e4.z + ern.z; es.z = es.z > 0.f ? es.z : 0.2f * es.z; es.z = __expf(es.z);
        es.w = e4.w + ern.w; es.w = es.w > 0.f ? es.w : 0.2f * es.w; es.w = __expf(es.w);
        asm volatile("" ::: "memory");    // fence: keep prior reads before the write
        *reinterpret_cast<float4*>(&wsh[wv][hw][hl * 4]) = es;
        asm volatile("" ::: "memory");    // fence: keep the write before the reads
        // same-wave LDS: HW executes the wave's DS ops in program order

        int cnt = min(32, row1 - base);
        const float* wp = &wsh[wv][hw][hh];
        int j = 0;
        for (; j + 4 <= cnt; j += 4) {
            int s0 = __shfl(sv, j, 32), s1 = __shfl(sv, j + 1, 32);
            int s2 = __shfl(sv, j + 2, 32), s3 = __shfl(sv, j + 3, 32);
            float w0 = wp[(j + 0) * 4], w1 = wp[(j + 1) * 4];
            float w2 = wp[(j + 2) * 4], w3 = wp[(j + 3) * 4];
            den += (w0 + w1) + (w2 + w3);
            if (V == 8) {
                half8_t a = *reinterpret_cast<const half8_t*>(hfeat + (size_t)s0 * F + f0);
                half8_t b = *reinterpret_cast<const half8_t*>(hfeat + (size_t)s1 * F + f0);
                half8_t c = *reinterpret_cast<const half8_t*>(hfeat + (size_t)s2 * F + f0);
                half8_t d = *reinterpret_cast<const half8_t*>(hfeat + (size_t)s3 * F + f0);
#pragma unroll
                for (int v = 0; v < V; ++v) {
                    ac0[v] = fmaf(w0, (float)a[v], ac0[v]);
                    ac1[v] = fmaf(w1, (float)b[v], ac1[v]);
                    ac2[v] = fmaf(w2, (float)c[v], ac2[v]);
                    ac3[v] = fmaf(w3, (float)d[v], ac3[v]);
                }
            } else {
                half4_t a = *reinterpret_cast<const half4_t*>(hfeat + (size_t)s0 * F + f0);
                half4_t b = *reinterpret_cast<const half4_t*>(hfeat + (size_t)s1 * F + f0);
                half4_t c = *reinterpret_cast<const half4_t*>(hfeat + (size_t)s2 * F + f0);
                half4_t d = *reinterpret_cast<const half4_t*>(hfeat + (size_t)s3 * F + f0);
#pragma unroll
                for (int v = 0; v < V; ++v) {
                    ac0[v] = fmaf(w0, (float)a[v], ac0[v]);
                    ac1[v] = fmaf(w1, (float)b[v], ac1[v]);
                    ac2[v] = fmaf(w2, (float)c[v], ac2[v]);
                    ac3[v] = fmaf(w3, (float)d[v], ac3[v]);
                }
            }
        }
        for (; j < cnt; ++j) {
            int s0 = __shfl(sv, j, 32);
            float w0 = wp[(size_t)j * 4];
            den += w0;
            if (V == 8) {
                half8_t a = *reinterpret_cast<const half8_t*>(hfeat + (size_t)s0 * F + f0);
#pragma unroll
                for (int v = 0; v < V; ++v) ac0[v] = fmaf(w0, (float)a[v], ac0[v]);
            } else {
                half4_t a = *reinterpret_cast<const half4_t*>(hfeat + (size_t)s0 * F + f0);
#pragma unroll
                for (int v = 0; v < V; ++v) ac0[v] = fmaf(w0, (float)a[v], ac0[v]);
            }
        }
        asm volatile("" ::: "memory");    // fence: next chunk's write stays after these reads
    }

    float inv = den > 0.f ? 1.f / den : 0.f;
    float val[V];
#pragma unroll
    for (int v = 0; v < V; ++v)
        val[v] = ((ac0[v] + ac1[v]) + (ac2[v] + ac3[v])) * inv + bias[f0 + v];

    if (MODE == 0) {
#pragma unroll
        for (int v = 0; v < V; ++v)
            val[v] = val[v] > 0.f ? val[v] : (__expf(val[v]) - 1.f);
        // V==4: 4 bf16 hi + 4 bf16 lo per lane, 8B stores
        unsigned int hpk[2], lpk[2];
#pragma unroll
        for (int q = 0; q < 2; ++q) {
            unsigned short h0 = f2bf(val[2 * q]), h1 = f2bf(val[2 * q + 1]);
            unsigned short l0 = f2bf(val[2 * q] - bf2f(h0));
            unsigned short l1 = f2bf(val[2 * q + 1] - bf2f(h1));
            hpk[q] = (unsigned int)h0 | ((unsigned int)h1 << 16);
            lpk[q] = (unsigned int)l0 | ((unsigned int)l1 << 16);
        }
        *reinterpret_cast<uint2*>(ohi + (size_t)wid * F + f0) = make_uint2(hpk[0], hpk[1]);
        *reinterpret_cast<uint2*>(olo + (size_t)wid * F + f0) = make_uint2(lpk[0], lpk[1]);
    } else {
        // head-mean over lanes {b, b+8, b+16, b+24} (b = hl&7), same tree as r7
#pragma unroll
        for (int v = 0; v < V; ++v) {
            val[v] += __shfl_xor(val[v], 8);
            val[v] += __shfl_xor(val[v], 16);
        }
        if (hl < 8) {
            float4 o0 = make_float4(val[0] * 0.25f, val[1] * 0.25f, val[2] * 0.25f, val[3] * 0.25f);
            float4 o1 = make_float4(val[4] * 0.25f, val[5] * 0.25f, val[6] * 0.25f, val[7] * 0.25f);
            *reinterpret_cast<float4*>(out + (size_t)wid * D + hl * 8) = o0;
            *reinterpret_cast<float4*>(out + (size_t)wid * D + hl * 8 + 4) = o1;
        }
    }
}

// ---------------------------------------------------------------- launch
extern "C" void kernel_launch(void* const* d_in, const int* in_sizes, int n_in,
                              void* d_out, int out_size, void* d_ws, size_t ws_size,
                              hipStream_t stream) {
    const float* nfeat = (const float*)d_in[0];
    const int* src = (const int*)d_in[1];
    const int* dst = (const int*)d_in[2];
    const float* W0 = (const float*)d_in[3];
    const float* al0 = (const float*)d_in[4];
    const float* ar0 = (const float*)d_in[5];
    const float* b0 = (const float*)d_in[6];
    const float* W1 = (const float*)d_in[7];
    const float* al1 = (const float*)d_in[8];
    const float* ar1 = (const float*)d_in[9];
    const float* b1 = (const float*)d_in[10];
    const float* W2 = (const float*)d_in[11];
    const float* al2 = (const float*)d_in[12];
    const float* ar2 = (const float*)d_in[13];
    const float* b2 = (const float*)d_in[14];
    float* out = (float*)d_out;

    char* w = (char*)d_ws;
    unsigned short* XA_hi = (unsigned short*)w; w += (size_t)N_NODES * 128 * 2;  // 25.6MB
    unsigned short* XA_lo = (unsigned short*)w; w += (size_t)N_NODES * 128 * 2;
    unsigned short* XB_hi = (unsigned short*)w; w += (size_t)N_NODES * 128 * 2;
    unsigned short* XB_lo = (unsigned short*)w; w += (size_t)N_NODES * 128 * 2;
    _Float16* Ph01 = (_Float16*)w; w += (size_t)N_NODES * 128 * 2;               // 25.6MB
    float* el = (float*)w;     w += (size_t)N_NODES * 4 * 4;
    float* er = (float*)w;     w += (size_t)N_NODES * 4 * 4;
    int* rowptr = (int*)w;     w += (size_t)(N_NODES + 4) * 4;
    int* deg = (int*)w;        w += (size_t)N_NODES * 4;
    int* bsum = (int*)w;       w += 256 * 4;
    int* csr_src = (int*)w;    w += (size_t)N_EDGES * 4;
    unsigned short* Wt0h = (unsigned short*)w; w += 16384 * 2;
    unsigned short* Wt0l = (unsigned short*)w; w += 16384 * 2;
    unsigned short* Wt1h = (unsigned short*)w; w += 16384 * 2;
    unsigned short* Wt1l = (unsigned short*)w; w += 16384 * 2;
    unsigned short* Wt2h = (unsigned short*)w; w += 32768 * 2;
    unsigned short* Wt2l = (unsigned short*)w; w += 32768 * 2;

    // Aliases (lifetime-checked):
    _Float16* H2h = (_Float16*)XB_hi; // 51.2MB spans XB_hi+XB_lo (dead at GEMM2)

    const int nb_scan = (N_NODES + 1023) / 1024;

    // ---- W converts
    convert_w_kernel<<<64, 256, 0, stream>>>(W0, Wt0h, Wt0l, 128);
    convert_w_kernel<<<64, 256, 0, stream>>>(W1, Wt1h, Wt1l, 128);
    convert_w_kernel<<<128, 256, 0, stream>>>(W2, Wt2h, Wt2l, 256);

    // ---- CSR build (bucketed scatter: write window per-XCD-L2-resident)
    hipMemsetAsync(deg, 0, (size_t)N_NODES * 4, stream);
    hist_kernel<<<(N_EDGES + 255) / 256, 256, 0, stream>>>(dst, deg);
    scan_block_kernel<<<nb_scan, 256, 0, stream>>>(deg, rowptr, bsum);
    scan_bsum_kernel<<<1, 128, 0, stream>>>(bsum, nb_scan);
    scan_add_kernel<<<(N_NODES + 256) / 256, 256, 0, stream>>>(rowptr, bsum);
    hipMemsetAsync(deg, 0, (size_t)N_NODES * 4, stream);
    {
        const int eb = (N_EDGES + 255) / 256;
        const int rs = (N_NODES + NPASS - 1) / NPASS;
        for (int p = 0; p < NPASS; ++p)
            scatter_pass_kernel<<<eb, 256, 0, stream>>>(src, dst, rowptr, deg, csr_src,
                                                        p * rs, min((p + 1) * rs, N_NODES));
    }

    const int ng_blocks = (N_NODES + 7) / 8;      // 2 nodes per wave
    dim3 gg1(782, 1), gg2(782, 2);

    // ---- Layer 0 (GEMM stages fp32 nfeat; fuses el/er + fp16 h)
    mfma_gemm_kernel<32, true><<<gg1, 256, 0, stream>>>(nullptr, nullptr, nfeat, Wt0h, Wt0l,
                                                        el, er, Ph01, N_NODES, 128, al0, ar0);
    sgather2_kernel<128, 0><<<ng_blocks, 256, 0, stream>>>(Ph01, el, er, rowptr, csr_src, b0,
                                                           nullptr, XB_hi, XB_lo);

    // ---- Layer 1
    mfma_gemm_kernel<32, false><<<gg1, 256, 0, stream>>>(XB_hi, XB_lo, nullptr, Wt1h, Wt1l,
                                                         el, er, Ph01, N_NODES, 128, al1, ar1);
    sgather2_kernel<128, 0><<<ng_blocks, 256, 0, stream>>>(Ph01, el, er, rowptr, csr_src, b1,
                                                           nullptr, XA_hi, XA_lo);

    // ---- Layer 2
    mfma_gemm_kernel<64, false><<<gg2, 256, 0, stream>>>(XA_hi, XA_lo, nullptr, Wt2h, Wt2l,
                                                         el, er, H2h, N_NODES, 256, al2, ar2);
    sgather2_kernel<256, 1><<<ng_blocks, 256, 0, stream>>>(H2h, el, er, rowptr, csr_src, b2,
                                                           out, nullptr, nullptr);
}